// Round 1
// baseline (25047.285 us; speedup 1.0000x reference)
//
#include <hip/hip_runtime.h>
#include <math.h>

#define B_ 4
#define T_ 1024
#define D_ 1024
#define H_ 16
#define DH_ 64
#define M_ 4096   // B*T rows
#define EPS_ 1e-5f

__device__ __forceinline__ float gelu_f(float x) {
  return 0.5f * x * (1.0f + erff(x * 0.70710678118654752f));
}

// ---------------- LayerNorm: one 256-thread block per row (D=1024) ----------------
__global__ __launch_bounds__(256) void ln_kernel(
    const float* __restrict__ in, float* __restrict__ out,
    const float* __restrict__ g, const float* __restrict__ b) {
  const int row = blockIdx.x;
  const int tid = threadIdx.x;
  const float* rp = in + (size_t)row * D_;
  float4 v = *reinterpret_cast<const float4*>(rp + tid * 4);
  float s = v.x + v.y + v.z + v.w;
  float s2 = v.x * v.x + v.y * v.y + v.z * v.z + v.w * v.w;
#pragma unroll
  for (int off = 1; off < 64; off <<= 1) {
    s += __shfl_xor(s, off);
    s2 += __shfl_xor(s2, off);
  }
  __shared__ float red[2][4];
  const int wid = tid >> 6;
  if ((tid & 63) == 0) { red[0][wid] = s; red[1][wid] = s2; }
  __syncthreads();
  s = red[0][0] + red[0][1] + red[0][2] + red[0][3];
  s2 = red[1][0] + red[1][1] + red[1][2] + red[1][3];
  const float mu = s * (1.0f / D_);
  const float var = s2 * (1.0f / D_) - mu * mu;
  const float rs = rsqrtf(var + EPS_);
  float4 gv = *reinterpret_cast<const float4*>(g + tid * 4);
  float4 bv = *reinterpret_cast<const float4*>(b + tid * 4);
  float4 o;
  o.x = (v.x - mu) * rs * gv.x + bv.x;
  o.y = (v.y - mu) * rs * gv.y + bv.y;
  o.z = (v.z - mu) * rs * gv.z + bv.z;
  o.w = (v.w - mu) * rs * gv.w + bv.w;
  *reinterpret_cast<float4*>(out + (size_t)row * D_ + tid * 4) = o;
}

// ---------------- fp32 GEMM: C[128x128 tile] op= A[M,K]@W[K,N] + bias ----------------
// MODE 0: store; MODE 1: C += result (residual accumulate); MODE 2: store gelu(result)
template<int MODE>
__global__ __launch_bounds__(256) void gemm128(
    const float* __restrict__ A, int lda,
    const float* __restrict__ W, int ldw,
    const float* __restrict__ bias,
    float* __restrict__ C, int ldc, int K) {
  __shared__ float As[16][132];  // [k][m], padded
  __shared__ float Bs[16][132];  // [k][n], padded
  const int gm = blockIdx.y * 128;
  const int gn = blockIdx.x * 128;
  const int tid = threadIdx.x;
  const int arow = tid >> 1, akq = (tid & 1) * 8;
  const int bk = tid >> 4, bn = (tid & 15) * 8;
  const int ty = tid >> 4, tx = tid & 15;
  float acc[8][8] = {};
  for (int kt = 0; kt < K; kt += 16) {
    const float* ap = A + (size_t)(gm + arow) * lda + kt + akq;
    float4 a0 = *reinterpret_cast<const float4*>(ap);
    float4 a1 = *reinterpret_cast<const float4*>(ap + 4);
    const float* wp = W + (size_t)(kt + bk) * ldw + gn + bn;
    float4 w0 = *reinterpret_cast<const float4*>(wp);
    float4 w1 = *reinterpret_cast<const float4*>(wp + 4);
    As[akq + 0][arow] = a0.x; As[akq + 1][arow] = a0.y;
    As[akq + 2][arow] = a0.z; As[akq + 3][arow] = a0.w;
    As[akq + 4][arow] = a1.x; As[akq + 5][arow] = a1.y;
    As[akq + 6][arow] = a1.z; As[akq + 7][arow] = a1.w;
    *reinterpret_cast<float4*>(&Bs[bk][bn]) = w0;
    *reinterpret_cast<float4*>(&Bs[bk][bn + 4]) = w1;
    __syncthreads();
#pragma unroll
    for (int kk = 0; kk < 16; ++kk) {
      float ar[8], br[8];
      *reinterpret_cast<float4*>(&ar[0]) = *reinterpret_cast<const float4*>(&As[kk][ty * 8]);
      *reinterpret_cast<float4*>(&ar[4]) = *reinterpret_cast<const float4*>(&As[kk][ty * 8 + 4]);
      *reinterpret_cast<float4*>(&br[0]) = *reinterpret_cast<const float4*>(&Bs[kk][tx * 8]);
      *reinterpret_cast<float4*>(&br[4]) = *reinterpret_cast<const float4*>(&Bs[kk][tx * 8 + 4]);
#pragma unroll
      for (int i = 0; i < 8; ++i)
#pragma unroll
        for (int j = 0; j < 8; ++j)
          acc[i][j] = fmaf(ar[i], br[j], acc[i][j]);
    }
    __syncthreads();
  }
  const int row0 = gm + ty * 8;
  const int col0 = gn + tx * 8;
  float bj[8] = {};
  if (bias) {
    *reinterpret_cast<float4*>(&bj[0]) = *reinterpret_cast<const float4*>(bias + col0);
    *reinterpret_cast<float4*>(&bj[4]) = *reinterpret_cast<const float4*>(bias + col0 + 4);
  }
#pragma unroll
  for (int i = 0; i < 8; ++i) {
    float r[8];
#pragma unroll
    for (int j = 0; j < 8; ++j) {
      r[j] = acc[i][j] + bj[j];
      if (MODE == 2) r[j] = gelu_f(r[j]);
    }
    float* cp = C + (size_t)(row0 + i) * ldc + col0;
    if (MODE == 1) {
      float4 c0 = *reinterpret_cast<float4*>(cp);
      float4 c1 = *reinterpret_cast<float4*>(cp + 4);
      r[0] += c0.x; r[1] += c0.y; r[2] += c0.z; r[3] += c0.w;
      r[4] += c1.x; r[5] += c1.y; r[6] += c1.z; r[7] += c1.w;
    }
    *reinterpret_cast<float4*>(cp) = make_float4(r[0], r[1], r[2], r[3]);
    *reinterpret_cast<float4*>(cp + 4) = make_float4(r[4], r[5], r[6], r[7]);
  }
}

// ---------------- Flash attention with block-causal mask ----------------
// grid (T/64, H, B), 256 threads. Thread t: query row r=t/4, quarter qt=t%4
// owns score cols qt*16..+15 and output dims qt*16..+15.
__global__ __launch_bounds__(256) void attn_kernel(
    const float* __restrict__ qg, const float* __restrict__ kg,
    const float* __restrict__ vg, float* __restrict__ yg) {
  const int qb = blockIdx.x;
  const int hh = blockIdx.y;
  const int bb = blockIdx.z;
  __shared__ float Qs[64][68];
  __shared__ float KVs[64][68];
  __shared__ float Ps[64][68];
  const int tid = threadIdx.x;
  const int r = tid >> 2, qt = tid & 3;
  const size_t base = (size_t)bb * T_ * D_ + (size_t)hh * DH_;

  // stage Q tile [64 rows x 64 dh]
#pragma unroll
  for (int u = 0; u < 4; ++u) {
    int e = (tid + u * 256) * 4;
    int rr = e >> 6, cc = e & 63;
    float4 t = *reinterpret_cast<const float4*>(qg + base + (size_t)(qb * 64 + rr) * D_ + cc);
    Qs[rr][cc] = t.x; Qs[rr][cc + 1] = t.y; Qs[rr][cc + 2] = t.z; Qs[rr][cc + 3] = t.w;
  }
  __syncthreads();
  float qreg[64];
#pragma unroll
  for (int u = 0; u < 16; ++u) {
    float4 t = *reinterpret_cast<const float4*>(&Qs[r][u * 4]);
    qreg[u * 4] = t.x; qreg[u * 4 + 1] = t.y; qreg[u * 4 + 2] = t.z; qreg[u * 4 + 3] = t.w;
  }

  float m_run = -INFINITY, l_run = 0.f;
  float o[16];
#pragma unroll
  for (int d = 0; d < 16; ++d) o[d] = 0.f;

  for (int kb = 0; kb <= qb; ++kb) {
    __syncthreads();  // protect KVs/Ps against previous iteration readers
    // stage K tile
#pragma unroll
    for (int u = 0; u < 4; ++u) {
      int e = (tid + u * 256) * 4;
      int rr = e >> 6, cc = e & 63;
      float4 t = *reinterpret_cast<const float4*>(kg + base + (size_t)(kb * 64 + rr) * D_ + cc);
      KVs[rr][cc] = t.x; KVs[rr][cc + 1] = t.y; KVs[rr][cc + 2] = t.z; KVs[rr][cc + 3] = t.w;
    }
    __syncthreads();
    float s[16];
#pragma unroll
    for (int c = 0; c < 16; ++c) {
      const int col = qt * 16 + c;
      float acc = 0.f;
#pragma unroll
      for (int u = 0; u < 16; ++u) {
        float4 k4 = *reinterpret_cast<const float4*>(&KVs[col][u * 4]);
        acc = fmaf(qreg[u * 4], k4.x, acc);
        acc = fmaf(qreg[u * 4 + 1], k4.y, acc);
        acc = fmaf(qreg[u * 4 + 2], k4.z, acc);
        acc = fmaf(qreg[u * 4 + 3], k4.w, acc);
      }
      s[c] = acc * 0.125f;
    }
    if (kb == qb) {
      // block-causal: within diagonal 64-tile, allowed col < (r/16+1)*16
      const int lim = (r >> 4) * 16 + 16;
#pragma unroll
      for (int c = 0; c < 16; ++c)
        if (qt * 16 + c >= lim) s[c] = -1e30f;
    }
    float tm = s[0];
#pragma unroll
    for (int c = 1; c < 16; ++c) tm = fmaxf(tm, s[c]);
    tm = fmaxf(tm, __shfl_xor(tm, 1));
    tm = fmaxf(tm, __shfl_xor(tm, 2));
    const float m_new = fmaxf(m_run, tm);
    const float alpha = expf(m_run - m_new);
    float tsum = 0.f;
#pragma unroll
    for (int c = 0; c < 16; ++c) { s[c] = expf(s[c] - m_new); tsum += s[c]; }
    tsum += __shfl_xor(tsum, 1);
    tsum += __shfl_xor(tsum, 2);
    l_run = l_run * alpha + tsum;
    m_run = m_new;
#pragma unroll
    for (int d = 0; d < 16; ++d) o[d] *= alpha;
#pragma unroll
    for (int c = 0; c < 16; ++c) Ps[r][qt * 16 + c] = s[c];
    __syncthreads();  // all S-reads of K done; all P writes done
    // stage V tile (overwrites KVs)
#pragma unroll
    for (int u = 0; u < 4; ++u) {
      int e = (tid + u * 256) * 4;
      int rr = e >> 6, cc = e & 63;
      float4 t = *reinterpret_cast<const float4*>(vg + base + (size_t)(kb * 64 + rr) * D_ + cc);
      KVs[rr][cc] = t.x; KVs[rr][cc + 1] = t.y; KVs[rr][cc + 2] = t.z; KVs[rr][cc + 3] = t.w;
    }
    __syncthreads();
    // PV accumulate
#pragma unroll
    for (int j = 0; j < 64; ++j) {
      float pj = Ps[r][j];
#pragma unroll
      for (int u = 0; u < 4; ++u) {
        float4 v4 = *reinterpret_cast<const float4*>(&KVs[j][qt * 16 + u * 4]);
        o[u * 4]     = fmaf(pj, v4.x, o[u * 4]);
        o[u * 4 + 1] = fmaf(pj, v4.y, o[u * 4 + 1]);
        o[u * 4 + 2] = fmaf(pj, v4.z, o[u * 4 + 2]);
        o[u * 4 + 3] = fmaf(pj, v4.w, o[u * 4 + 3]);
      }
    }
  }
  const float inv = 1.0f / l_run;
  float* yp = yg + base + (size_t)(qb * 64 + r) * D_ + qt * 16;
#pragma unroll
  for (int u = 0; u < 4; ++u) {
    float4 t;
    t.x = o[u * 4] * inv; t.y = o[u * 4 + 1] * inv;
    t.z = o[u * 4 + 2] * inv; t.w = o[u * 4 + 3] * inv;
    *reinterpret_cast<float4*>(yp + u * 4) = t;
  }
}

extern "C" void kernel_launch(void* const* d_in, const int* in_sizes, int n_in,
                              void* d_out, int out_size, void* d_ws, size_t ws_size,
                              hipStream_t stream) {
  (void)in_sizes; (void)n_in; (void)out_size; (void)ws_size;
  const float* seq  = (const float*)d_in[0];
  const float* Wq   = (const float*)d_in[1];
  const float* bq   = (const float*)d_in[2];
  const float* Wk   = (const float*)d_in[3];
  const float* bk   = (const float*)d_in[4];
  const float* Wv   = (const float*)d_in[5];
  const float* bv   = (const float*)d_in[6];
  const float* Wp   = (const float*)d_in[7];
  const float* bp   = (const float*)d_in[8];
  const float* ln1g = (const float*)d_in[9];
  const float* ln1b = (const float*)d_in[10];
  const float* ln2g = (const float*)d_in[11];
  const float* ln2b = (const float*)d_in[12];
  const float* W1   = (const float*)d_in[13];
  const float* b1   = (const float*)d_in[14];
  const float* W2   = (const float*)d_in[15];
  const float* b2   = (const float*)d_in[16];
  const float* lnfg = (const float*)d_in[17];
  const float* lnfb = (const float*)d_in[18];

  float* x  = (float*)d_out;        // residual stream lives in d_out
  float* ws = (float*)d_ws;
  const size_t TD = (size_t)M_ * D_;  // 4M floats
  float* qb_ = ws;
  float* kb_ = ws + TD;
  float* vb_ = ws + 2 * TD;
  float* hb_ = ws + 3 * TD;          // h / y / h2 (reused)
  float* mid = ws + 4 * TD;          // FFN mid chunk [4096 x 1024]

  hipMemcpyAsync(x, seq, TD * sizeof(float), hipMemcpyDeviceToDevice, stream);

  const dim3 blk(256);
  const dim3 gemmGrid(8, 32);  // N=1024 -> 8 tiles, M=4096 -> 32 tiles

  for (int i = 0; i < 8; ++i) {
    const size_t wo  = (size_t)i * D_ * D_;
    const size_t vo  = (size_t)i * D_;
    const size_t w1o = (size_t)i * D_ * 4 * D_;

    ln_kernel<<<M_, blk, 0, stream>>>(x, hb_, ln1g + vo, ln1b + vo);
    gemm128<0><<<gemmGrid, blk, 0, stream>>>(hb_, D_, Wq + wo, D_, bq + vo, qb_, D_, D_);
    gemm128<0><<<gemmGrid, blk, 0, stream>>>(hb_, D_, Wk + wo, D_, bk + vo, kb_, D_, D_);
    gemm128<0><<<gemmGrid, blk, 0, stream>>>(hb_, D_, Wv + wo, D_, bv + vo, vb_, D_, D_);
    attn_kernel<<<dim3(16, 16, 4), blk, 0, stream>>>(qb_, kb_, vb_, hb_);
    gemm128<1><<<gemmGrid, blk, 0, stream>>>(hb_, D_, Wp + wo, D_, bp + vo, x, D_, D_);
    ln_kernel<<<M_, blk, 0, stream>>>(x, hb_, ln2g + vo, ln2b + vo);
    for (int c = 0; c < 4; ++c) {
      gemm128<2><<<gemmGrid, blk, 0, stream>>>(
          hb_, D_, W1 + w1o + c * 1024, 4 * D_,
          b1 + (size_t)i * 4 * D_ + c * 1024, mid, D_, D_);
      gemm128<1><<<gemmGrid, blk, 0, stream>>>(
          mid, D_, W2 + w1o + (size_t)c * 1024 * D_, D_,
          (c == 0 ? b2 + vo : nullptr), x, D_, D_);
    }
  }
  ln_kernel<<<M_, blk, 0, stream>>>(x, x, lnfg, lnfb);
}

// Round 2
// 7816.714 us; speedup vs baseline: 3.2043x; 3.2043x over previous
//
#include <hip/hip_runtime.h>
#include <hip/hip_bf16.h>
#include <math.h>

#define B_ 4
#define T_ 1024
#define D_ 1024
#define H_ 16
#define DH_ 64
#define M_ 4096
#define EPS_ 1e-5f

typedef __attribute__((ext_vector_type(4))) float f32x4;
typedef __attribute__((ext_vector_type(8))) short s16x8;

__device__ __forceinline__ float gelu_f(float x) {
  return 0.5f * x * (1.0f + erff(x * 0.70710678118654752f));
}
__device__ __forceinline__ float b2f(unsigned short u) {
  union { unsigned int i; float f; } c; c.i = ((unsigned int)u) << 16; return c.f;
}
__device__ __forceinline__ unsigned short f2b(float f) {
  __hip_bfloat16 h = __float2bfloat16(f);
  return *reinterpret_cast<unsigned short*>(&h);
}
__device__ __forceinline__ void g2l16(void* l, const void* g) {
  __builtin_amdgcn_global_load_lds(
      (const __attribute__((address_space(1))) void*)g,
      (__attribute__((address_space(3))) void*)l, 16, 0, 0);
}

// ---------------- LayerNorm ----------------
template<bool BF16OUT>
__global__ __launch_bounds__(256) void ln_kernel(
    const float* __restrict__ in, void* __restrict__ out,
    const float* __restrict__ g, const float* __restrict__ b) {
  const int row = blockIdx.x;
  const int tid = threadIdx.x;
  const float* rp = in + (size_t)row * D_;
  float4 v = *reinterpret_cast<const float4*>(rp + tid * 4);
  float s = v.x + v.y + v.z + v.w;
  float s2 = v.x * v.x + v.y * v.y + v.z * v.z + v.w * v.w;
#pragma unroll
  for (int off = 1; off < 64; off <<= 1) {
    s += __shfl_xor(s, off);
    s2 += __shfl_xor(s2, off);
  }
  __shared__ float red[2][4];
  const int wid = tid >> 6;
  if ((tid & 63) == 0) { red[0][wid] = s; red[1][wid] = s2; }
  __syncthreads();
  s = red[0][0] + red[0][1] + red[0][2] + red[0][3];
  s2 = red[1][0] + red[1][1] + red[1][2] + red[1][3];
  const float mu = s * (1.0f / D_);
  const float var = s2 * (1.0f / D_) - mu * mu;
  const float rs = rsqrtf(var + EPS_);
  float4 gv = *reinterpret_cast<const float4*>(g + tid * 4);
  float4 bv = *reinterpret_cast<const float4*>(b + tid * 4);
  float o0 = (v.x - mu) * rs * gv.x + bv.x;
  float o1 = (v.y - mu) * rs * gv.y + bv.y;
  float o2 = (v.z - mu) * rs * gv.z + bv.z;
  float o3 = (v.w - mu) * rs * gv.w + bv.w;
  if (BF16OUT) {
    ushort4 pk;
    pk.x = f2b(o0); pk.y = f2b(o1); pk.z = f2b(o2); pk.w = f2b(o3);
    *reinterpret_cast<ushort4*>((unsigned short*)out + (size_t)row * D_ + tid * 4) = pk;
  } else {
    *reinterpret_cast<float4*>((float*)out + (size_t)row * D_ + tid * 4) =
        make_float4(o0, o1, o2, o3);
  }
}

// ---------------- transpose fp32 [K][N] -> bf16 [N][K] ----------------
__device__ __forceinline__ void transpose_tile(
    const float* __restrict__ src, int sld,
    __hip_bfloat16* __restrict__ dst, int dld, int k0, int n0) {
  __shared__ float tile[32][33];
  const int t = threadIdx.x;
  const int r = t >> 3;
  const int cq = (t & 7) * 4;
  float4 vv = *reinterpret_cast<const float4*>(src + (size_t)(k0 + r) * sld + n0 + cq);
  tile[r][cq + 0] = vv.x; tile[r][cq + 1] = vv.y;
  tile[r][cq + 2] = vv.z; tile[r][cq + 3] = vv.w;
  __syncthreads();
  ushort4 o;
  o.x = f2b(tile[cq + 0][r]); o.y = f2b(tile[cq + 1][r]);
  o.z = f2b(tile[cq + 2][r]); o.w = f2b(tile[cq + 3][r]);
  *reinterpret_cast<ushort4*>((unsigned short*)dst + (size_t)(n0 + r) * dld + k0 + cq) = o;
}

struct TPack { const float* s[4]; __hip_bfloat16* d[4]; };

__global__ __launch_bounds__(256) void transpose4(TPack p) {
  transpose_tile(p.s[blockIdx.z], 1024, p.d[blockIdx.z], 1024,
                 blockIdx.x * 32, blockIdx.y * 32);
}
__global__ __launch_bounds__(256) void transpose1(
    const float* __restrict__ src, int sld,
    __hip_bfloat16* __restrict__ dst, int dld) {
  transpose_tile(src, sld, dst, dld, blockIdx.x * 32, blockIdx.y * 32);
}

// ---------------- bf16 MFMA GEMM: C = A[M,K] @ Bt[N,K]^T + bias ----------------
// MODE 0: store bf16; MODE 1: fp32 C += result; MODE 2: store bf16 gelu(result)
template<int MODE>
__global__ __launch_bounds__(256) void gemm_mfma(
    const __hip_bfloat16* __restrict__ A,
    const __hip_bfloat16* __restrict__ Bt,
    const float* __restrict__ bias,
    void* __restrict__ Cout, int N, int K) {
  __shared__ short As[128 * 32];  // [row][k] bf16 linear
  __shared__ short Bs[128 * 32];
  const int gn = blockIdx.x * 128;
  const int gm = blockIdx.y * 128;
  const int tid = threadIdx.x;
  const int wid = tid >> 6, lane = tid & 63;
  const int wm = wid >> 1, wn = wid & 1;
  const int fr = lane & 15, kg = lane >> 4;

  f32x4 acc[4][4] = {};
  for (int kt = 0; kt < K; kt += 32) {
#pragma unroll
    for (int u = 0; u < 2; ++u) {
      const int rowa = (wid * 2 + u) * 16 + (lane >> 2);
      const int kk = (lane & 3) * 8;
      g2l16((char*)As + (wid * 2 + u) * 1024,
            A + (size_t)(gm + rowa) * K + kt + kk);
      g2l16((char*)Bs + (wid * 2 + u) * 1024,
            Bt + (size_t)(gn + rowa) * K + kt + kk);
    }
    asm volatile("s_waitcnt vmcnt(0)" ::: "memory");
    __syncthreads();
    s16x8 af[4], bfr[4];
#pragma unroll
    for (int m = 0; m < 4; ++m)
      af[m] = *reinterpret_cast<const s16x8*>(&As[(wm * 64 + m * 16 + fr) * 32 + kg * 8]);
#pragma unroll
    for (int n = 0; n < 4; ++n)
      bfr[n] = *reinterpret_cast<const s16x8*>(&Bs[(wn * 64 + n * 16 + fr) * 32 + kg * 8]);
#pragma unroll
    for (int m = 0; m < 4; ++m)
#pragma unroll
      for (int n = 0; n < 4; ++n)
        acc[m][n] = __builtin_amdgcn_mfma_f32_16x16x32_bf16(af[m], bfr[n], acc[m][n], 0, 0, 0);
    __syncthreads();
  }

  const int r0 = gm + wm * 64;
  const int c0 = gn + wn * 64;
  float bb[4];
#pragma unroll
  for (int n = 0; n < 4; ++n)
    bb[n] = bias ? bias[c0 + n * 16 + fr] : 0.0f;
#pragma unroll
  for (int m = 0; m < 4; ++m) {
#pragma unroll
    for (int j = 0; j < 4; ++j) {
      const int row = r0 + m * 16 + kg * 4 + j;
#pragma unroll
      for (int n = 0; n < 4; ++n) {
        float val = acc[m][n][j] + bb[n];
        const size_t idx = (size_t)row * N + c0 + n * 16 + fr;
        if (MODE == 0) {
          ((unsigned short*)Cout)[idx] = f2b(val);
        } else if (MODE == 1) {
          float* cp = (float*)Cout + idx;
          *cp = *cp + val;
        } else {
          ((unsigned short*)Cout)[idx] = f2b(gelu_f(val));
        }
      }
    }
  }
}

// ---------------- Flash attention (fp32 math, bf16 I/O), block-causal ----------------
__global__ __launch_bounds__(256) void attn_kernel(
    const __hip_bfloat16* __restrict__ qg, const __hip_bfloat16* __restrict__ kg,
    const __hip_bfloat16* __restrict__ vg, __hip_bfloat16* __restrict__ yg) {
  const int qb = 15 - blockIdx.x;  // heavy tiles first
  const int hh = blockIdx.y;
  const int bb = blockIdx.z;
  __shared__ float Qs[64][68];   // later reused as P (stride 68)
  __shared__ float KV[64 * 64];  // swizzled
  const int tid = threadIdx.x;
  const int r = tid >> 2, qt = tid & 3;
  const size_t base = (size_t)bb * T_ * D_ + (size_t)hh * DH_;

#pragma unroll
  for (int u = 0; u < 2; ++u) {
    const int e = (tid + u * 256) * 8;
    const int rr = e >> 6, cc = e & 63;
    s16x8 raw = *reinterpret_cast<const s16x8*>(
        (const unsigned short*)qg + base + (size_t)(qb * 64 + rr) * D_ + cc);
#pragma unroll
    for (int j = 0; j < 8; ++j) Qs[rr][cc + j] = b2f((unsigned short)raw[j]);
  }
  __syncthreads();
  float qreg[64];
#pragma unroll
  for (int u = 0; u < 16; ++u) {
    float4 t4 = *reinterpret_cast<const float4*>(&Qs[r][u * 4]);
    qreg[u * 4] = t4.x; qreg[u * 4 + 1] = t4.y;
    qreg[u * 4 + 2] = t4.z; qreg[u * 4 + 3] = t4.w;
  }
  float* Ps = &Qs[0][0];  // stride 68

  float m_run = -INFINITY, l_run = 0.f;
  float o[16];
#pragma unroll
  for (int d = 0; d < 16; ++d) o[d] = 0.f;

  for (int kb = 0; kb <= qb; ++kb) {
    __syncthreads();
    // stage K (swizzled)
#pragma unroll
    for (int u = 0; u < 2; ++u) {
      const int e = (tid + u * 256) * 8;
      const int rr = e >> 6, cc = e & 63;
      s16x8 raw = *reinterpret_cast<const s16x8*>(
          (const unsigned short*)kg + base + (size_t)(kb * 64 + rr) * D_ + cc);
      float f[8];
#pragma unroll
      for (int j = 0; j < 8; ++j) f[j] = b2f((unsigned short)raw[j]);
      const int sw = (rr >> 4) & 3;
#pragma unroll
      for (int c2 = 0; c2 < 2; ++c2) {
        const int slot = ((cc >> 2) + c2) ^ sw;
        *reinterpret_cast<float4*>(&KV[rr * 64 + slot * 4]) =
            make_float4(f[c2 * 4], f[c2 * 4 + 1], f[c2 * 4 + 2], f[c2 * 4 + 3]);
      }
    }
    __syncthreads();
    float s[16];
#pragma unroll
    for (int c = 0; c < 16; ++c) {
      const int col = qt * 16 + c;
      const int sw = (col >> 4) & 3;
      float acc = 0.f;
#pragma unroll
      for (int u = 0; u < 16; ++u) {
        float4 k4 = *reinterpret_cast<const float4*>(&KV[col * 64 + ((u ^ sw) << 2)]);
        acc = fmaf(qreg[u * 4], k4.x, acc);
        acc = fmaf(qreg[u * 4 + 1], k4.y, acc);
        acc = fmaf(qreg[u * 4 + 2], k4.z, acc);
        acc = fmaf(qreg[u * 4 + 3], k4.w, acc);
      }
      s[c] = acc * 0.125f;
    }
    if (kb == qb) {
      const int lim = (r >> 4) * 16 + 16;
#pragma unroll
      for (int c = 0; c < 16; ++c)
        if (qt * 16 + c >= lim) s[c] = -1e30f;
    }
    float tm = s[0];
#pragma unroll
    for (int c = 1; c < 16; ++c) tm = fmaxf(tm, s[c]);
    tm = fmaxf(tm, __shfl_xor(tm, 1));
    tm = fmaxf(tm, __shfl_xor(tm, 2));
    const float m_new = fmaxf(m_run, tm);
    const float alpha = expf(m_run - m_new);
    float tsum = 0.f;
#pragma unroll
    for (int c = 0; c < 16; ++c) { s[c] = expf(s[c] - m_new); tsum += s[c]; }
    tsum += __shfl_xor(tsum, 1);
    tsum += __shfl_xor(tsum, 2);
    l_run = l_run * alpha + tsum;
    m_run = m_new;
#pragma unroll
    for (int d = 0; d < 16; ++d) o[d] *= alpha;
#pragma unroll
    for (int c = 0; c < 16; ++c) Ps[r * 68 + qt * 16 + c] = s[c];
    __syncthreads();
    // stage V (swizzled, overwrites KV)
#pragma unroll
    for (int u = 0; u < 2; ++u) {
      const int e = (tid + u * 256) * 8;
      const int rr = e >> 6, cc = e & 63;
      s16x8 raw = *reinterpret_cast<const s16x8*>(
          (const unsigned short*)vg + base + (size_t)(kb * 64 + rr) * D_ + cc);
      float f[8];
#pragma unroll
      for (int j = 0; j < 8; ++j) f[j] = b2f((unsigned short)raw[j]);
      const int sw = (rr >> 4) & 3;
#pragma unroll
      for (int c2 = 0; c2 < 2; ++c2) {
        const int slot = ((cc >> 2) + c2) ^ sw;
        *reinterpret_cast<float4*>(&KV[rr * 64 + slot * 4]) =
            make_float4(f[c2 * 4], f[c2 * 4 + 1], f[c2 * 4 + 2], f[c2 * 4 + 3]);
      }
    }
    __syncthreads();
#pragma unroll
    for (int j2 = 0; j2 < 64; ++j2) {
      const float pj = Ps[r * 68 + j2];
      const int sw = (j2 >> 4) & 3;
#pragma unroll
      for (int u = 0; u < 4; ++u) {
        float4 v4 = *reinterpret_cast<const float4*>(
            &KV[j2 * 64 + (((qt * 4 + u) ^ sw) << 2)]);
        o[u * 4]     = fmaf(pj, v4.x, o[u * 4]);
        o[u * 4 + 1] = fmaf(pj, v4.y, o[u * 4 + 1]);
        o[u * 4 + 2] = fmaf(pj, v4.z, o[u * 4 + 2]);
        o[u * 4 + 3] = fmaf(pj, v4.w, o[u * 4 + 3]);
      }
    }
  }
  const float inv = 1.0f / l_run;
  unsigned short* yp = (unsigned short*)yg + base + (size_t)(qb * 64 + r) * D_ + qt * 16;
#pragma unroll
  for (int u = 0; u < 4; ++u) {
    ushort4 pk;
    pk.x = f2b(o[u * 4] * inv);     pk.y = f2b(o[u * 4 + 1] * inv);
    pk.z = f2b(o[u * 4 + 2] * inv); pk.w = f2b(o[u * 4 + 3] * inv);
    *reinterpret_cast<ushort4*>(yp + u * 4) = pk;
  }
}

extern "C" void kernel_launch(void* const* d_in, const int* in_sizes, int n_in,
                              void* d_out, int out_size, void* d_ws, size_t ws_size,
                              hipStream_t stream) {
  (void)in_sizes; (void)n_in; (void)out_size;
  const float* seq  = (const float*)d_in[0];
  const float* Wq   = (const float*)d_in[1];
  const float* bq   = (const float*)d_in[2];
  const float* Wk   = (const float*)d_in[3];
  const float* bk   = (const float*)d_in[4];
  const float* Wv   = (const float*)d_in[5];
  const float* bv   = (const float*)d_in[6];
  const float* Wp   = (const float*)d_in[7];
  const float* bp   = (const float*)d_in[8];
  const float* ln1g = (const float*)d_in[9];
  const float* ln1b = (const float*)d_in[10];
  const float* ln2g = (const float*)d_in[11];
  const float* ln2b = (const float*)d_in[12];
  const float* W1   = (const float*)d_in[13];
  const float* b1   = (const float*)d_in[14];
  const float* W2   = (const float*)d_in[15];
  const float* b2   = (const float*)d_in[16];
  const float* lnfg = (const float*)d_in[17];
  const float* lnfb = (const float*)d_in[18];

  float* x = (float*)d_out;
  char* ws = (char*)d_ws;
  const size_t MB = 1024ull * 1024ull;
  typedef __hip_bfloat16 bf16;
  bf16* wtq  = (bf16*)(ws + 0 * MB);
  bf16* wtk  = (bf16*)(ws + 2 * MB);
  bf16* wtv  = (bf16*)(ws + 4 * MB);
  bf16* wtp  = (bf16*)(ws + 6 * MB);
  bf16* wtF1 = (bf16*)(ws + 8 * MB);
  bf16* wtF2 = (bf16*)(ws + 16 * MB);
  bf16* hb   = (bf16*)(ws + 24 * MB);
  bf16* qb_  = (bf16*)(ws + 32 * MB);
  bf16* kb_  = (bf16*)(ws + 40 * MB);
  bf16* vb_  = (bf16*)(ws + 48 * MB);
  bf16* mid  = (bf16*)(ws + 56 * MB);
  const int CS = (ws_size >= 92 * MB) ? 4096 : 1024;  // FFN column chunk
  const int NC = 4096 / CS;

  hipMemcpyAsync(x, seq, (size_t)M_ * D_ * sizeof(float), hipMemcpyDeviceToDevice, stream);

  const dim3 blk(256);
  for (int i = 0; i < 8; ++i) {
    const size_t wo  = (size_t)i * D_ * D_;
    const size_t vo  = (size_t)i * D_;
    const size_t w1o = (size_t)i * D_ * 4 * D_;

    ln_kernel<true><<<M_, blk, 0, stream>>>(x, hb, ln1g + vo, ln1b + vo);
    TPack tp;
    tp.s[0] = Wq + wo; tp.s[1] = Wk + wo; tp.s[2] = Wv + wo; tp.s[3] = Wp + wo;
    tp.d[0] = wtq; tp.d[1] = wtk; tp.d[2] = wtv; tp.d[3] = wtp;
    transpose4<<<dim3(32, 32, 4), blk, 0, stream>>>(tp);
    gemm_mfma<0><<<dim3(8, 32), blk, 0, stream>>>(hb, wtq, bq + vo, qb_, 1024, 1024);
    gemm_mfma<0><<<dim3(8, 32), blk, 0, stream>>>(hb, wtk, bk + vo, kb_, 1024, 1024);
    gemm_mfma<0><<<dim3(8, 32), blk, 0, stream>>>(hb, wtv, bv + vo, vb_, 1024, 1024);
    attn_kernel<<<dim3(16, 16, 4), blk, 0, stream>>>(qb_, kb_, vb_, hb);
    gemm_mfma<1><<<dim3(8, 32), blk, 0, stream>>>(hb, wtp, bp + vo, x, 1024, 1024);
    ln_kernel<true><<<M_, blk, 0, stream>>>(x, hb, ln2g + vo, ln2b + vo);
    for (int c = 0; c < NC; ++c) {
      // W1 chunk: src [1024][4096] cols c*CS.. -> wtF1 [CS][1024]
      transpose1<<<dim3(32, CS / 32), blk, 0, stream>>>(W1 + w1o + c * CS, 4096, wtF1, 1024);
      gemm_mfma<2><<<dim3(CS / 128, 32), blk, 0, stream>>>(
          hb, wtF1, b1 + (size_t)i * 4096 + c * CS, mid, CS, 1024);
      // W2 chunk: src rows c*CS.. [CS][1024] -> wtF2 [1024][CS]
      transpose1<<<dim3(CS / 32, 32), blk, 0, stream>>>(W2 + w1o + (size_t)c * CS * 1024, 1024, wtF2, CS);
      gemm_mfma<1><<<dim3(8, 32), blk, 0, stream>>>(
          mid, wtF2, (c == 0 ? b2 + vo : nullptr), x, 1024, CS);
    }
  }
  ln_kernel<false><<<M_, blk, 0, stream>>>(x, x, lnfg, lnfb);
}

// Round 3
// 3011.020 us; speedup vs baseline: 8.3185x; 2.5960x over previous
//
#include <hip/hip_runtime.h>
#include <hip/hip_bf16.h>
#include <math.h>

#define B_ 4
#define T_ 1024
#define D_ 1024
#define H_ 16
#define DH_ 64
#define M_ 4096
#define EPS_ 1e-5f

typedef __attribute__((ext_vector_type(4))) float f32x4;
typedef __attribute__((ext_vector_type(8))) short s16x8;

#if __has_builtin(__builtin_amdgcn_exp2f)
#define EXP2F __builtin_amdgcn_exp2f
#else
#define EXP2F exp2f
#endif

__device__ __forceinline__ float gelu_f(float x) {
  return 0.5f * x * (1.0f + erff(x * 0.70710678118654752f));
}
__device__ __forceinline__ float b2f(unsigned short u) {
  union { unsigned int i; float f; } c; c.i = ((unsigned int)u) << 16; return c.f;
}
__device__ __forceinline__ unsigned short f2b(float f) {
  __hip_bfloat16 h = __float2bfloat16(f);
  return *reinterpret_cast<unsigned short*>(&h);
}
__device__ __forceinline__ void g2l16(void* l, const void* g) {
  __builtin_amdgcn_global_load_lds(
      (const __attribute__((address_space(1))) void*)g,
      (__attribute__((address_space(3))) void*)l, 16, 0, 0);
}

// ---------------- LayerNorm ----------------
template<bool BF16OUT>
__global__ __launch_bounds__(256) void ln_kernel(
    const float* __restrict__ in, void* __restrict__ out,
    const float* __restrict__ g, const float* __restrict__ b) {
  const int row = blockIdx.x;
  const int tid = threadIdx.x;
  const float* rp = in + (size_t)row * D_;
  float4 v = *reinterpret_cast<const float4*>(rp + tid * 4);
  float s = v.x + v.y + v.z + v.w;
  float s2 = v.x * v.x + v.y * v.y + v.z * v.z + v.w * v.w;
#pragma unroll
  for (int off = 1; off < 64; off <<= 1) {
    s += __shfl_xor(s, off);
    s2 += __shfl_xor(s2, off);
  }
  __shared__ float red[2][4];
  const int wid = tid >> 6;
  if ((tid & 63) == 0) { red[0][wid] = s; red[1][wid] = s2; }
  __syncthreads();
  s = red[0][0] + red[0][1] + red[0][2] + red[0][3];
  s2 = red[1][0] + red[1][1] + red[1][2] + red[1][3];
  const float mu = s * (1.0f / D_);
  const float var = s2 * (1.0f / D_) - mu * mu;
  const float rs = rsqrtf(var + EPS_);
  float4 gv = *reinterpret_cast<const float4*>(g + tid * 4);
  float4 bv = *reinterpret_cast<const float4*>(b + tid * 4);
  float o0 = (v.x - mu) * rs * gv.x + bv.x;
  float o1 = (v.y - mu) * rs * gv.y + bv.y;
  float o2 = (v.z - mu) * rs * gv.z + bv.z;
  float o3 = (v.w - mu) * rs * gv.w + bv.w;
  if (BF16OUT) {
    ushort4 pk;
    pk.x = f2b(o0); pk.y = f2b(o1); pk.z = f2b(o2); pk.w = f2b(o3);
    *reinterpret_cast<ushort4*>((unsigned short*)out + (size_t)row * D_ + tid * 4) = pk;
  } else {
    *reinterpret_cast<float4*>((float*)out + (size_t)row * D_ + tid * 4) =
        make_float4(o0, o1, o2, o3);
  }
}

// ---------------- transpose fp32 [K][N] -> bf16 [N][K] ----------------
__device__ __forceinline__ void transpose_tile(
    const float* __restrict__ src, int sld,
    __hip_bfloat16* __restrict__ dst, int dld, int k0, int n0) {
  __shared__ float tile[32][33];
  const int t = threadIdx.x;
  const int r = t >> 3;
  const int cq = (t & 7) * 4;
  float4 vv = *reinterpret_cast<const float4*>(src + (size_t)(k0 + r) * sld + n0 + cq);
  tile[r][cq + 0] = vv.x; tile[r][cq + 1] = vv.y;
  tile[r][cq + 2] = vv.z; tile[r][cq + 3] = vv.w;
  __syncthreads();
  ushort4 o;
  o.x = f2b(tile[cq + 0][r]); o.y = f2b(tile[cq + 1][r]);
  o.z = f2b(tile[cq + 2][r]); o.w = f2b(tile[cq + 3][r]);
  *reinterpret_cast<ushort4*>((unsigned short*)dst + (size_t)(n0 + r) * dld + k0 + cq) = o;
}

struct TPack { const float* s[4]; __hip_bfloat16* d[4]; };

__global__ __launch_bounds__(256) void transpose4(TPack p) {
  transpose_tile(p.s[blockIdx.z], 1024, p.d[blockIdx.z], 1024,
                 blockIdx.x * 32, blockIdx.y * 32);
}
__global__ __launch_bounds__(256) void transpose1(
    const float* __restrict__ src, int sld,
    __hip_bfloat16* __restrict__ dst, int dld) {
  transpose_tile(src, sld, dst, dld, blockIdx.x * 32, blockIdx.y * 32);
}

// ---------------- bf16 MFMA GEMM: C = A[M,K] @ Bt[N,K]^T + bias ----------------
template<int MODE>
__global__ __launch_bounds__(256) void gemm_mfma(
    const __hip_bfloat16* __restrict__ A,
    const __hip_bfloat16* __restrict__ Bt,
    const float* __restrict__ bias,
    void* __restrict__ Cout, int N, int K) {
  __shared__ short As[128 * 32];
  __shared__ short Bs[128 * 32];
  const int gn = blockIdx.x * 128;
  const int gm = blockIdx.y * 128;
  const int tid = threadIdx.x;
  const int wid = tid >> 6, lane = tid & 63;
  const int wm = wid >> 1, wn = wid & 1;
  const int fr = lane & 15, kg = lane >> 4;

  f32x4 acc[4][4] = {};
  for (int kt = 0; kt < K; kt += 32) {
#pragma unroll
    for (int u = 0; u < 2; ++u) {
      const int rowa = (wid * 2 + u) * 16 + (lane >> 2);
      const int kk = (lane & 3) * 8;
      g2l16((char*)As + (wid * 2 + u) * 1024,
            A + (size_t)(gm + rowa) * K + kt + kk);
      g2l16((char*)Bs + (wid * 2 + u) * 1024,
            Bt + (size_t)(gn + rowa) * K + kt + kk);
    }
    asm volatile("s_waitcnt vmcnt(0)" ::: "memory");
    __syncthreads();
    s16x8 af[4], bfr[4];
#pragma unroll
    for (int m = 0; m < 4; ++m)
      af[m] = *reinterpret_cast<const s16x8*>(&As[(wm * 64 + m * 16 + fr) * 32 + kg * 8]);
#pragma unroll
    for (int n = 0; n < 4; ++n)
      bfr[n] = *reinterpret_cast<const s16x8*>(&Bs[(wn * 64 + n * 16 + fr) * 32 + kg * 8]);
#pragma unroll
    for (int m = 0; m < 4; ++m)
#pragma unroll
      for (int n = 0; n < 4; ++n)
        acc[m][n] = __builtin_amdgcn_mfma_f32_16x16x32_bf16(af[m], bfr[n], acc[m][n], 0, 0, 0);
    __syncthreads();
  }

  const int r0 = gm + wm * 64;
  const int c0 = gn + wn * 64;
  float bb[4];
#pragma unroll
  for (int n = 0; n < 4; ++n)
    bb[n] = bias ? bias[c0 + n * 16 + fr] : 0.0f;
#pragma unroll
  for (int m = 0; m < 4; ++m) {
#pragma unroll
    for (int j = 0; j < 4; ++j) {
      const int row = r0 + m * 16 + kg * 4 + j;
#pragma unroll
      for (int n = 0; n < 4; ++n) {
        float val = acc[m][n][j] + bb[n];
        const size_t idx = (size_t)row * N + c0 + n * 16 + fr;
        if (MODE == 0) {
          ((unsigned short*)Cout)[idx] = f2b(val);
        } else if (MODE == 1) {
          float* cp = (float*)Cout + idx;
          *cp = *cp + val;
        } else {
          ((unsigned short*)Cout)[idx] = f2b(gelu_f(val));
        }
      }
    }
  }
}

// ---------------- MFMA flash attention, block-causal ----------------
// grid (16,16,4): x->qb(desc), y->head, z->batch. 4 waves, wave = 16 q-rows.
// All 64x64 bf16 tiles in LDS use swizzle: elem (r,c) at byte
//   r*128 + (((c>>3)^(r&7))<<4) + (c&7)*2
__global__ __launch_bounds__(256) void attn_mfma(
    const __hip_bfloat16* __restrict__ qg, const __hip_bfloat16* __restrict__ kg,
    const __hip_bfloat16* __restrict__ vg, __hip_bfloat16* __restrict__ yg) {
  const int qb = 15 - blockIdx.x;
  const int hh = blockIdx.y;
  const int bb = blockIdx.z;
  __shared__ short Ks[64 * 64];
  __shared__ short Vt[64 * 64];  // V transposed: row=d, col=k
  __shared__ short Ps[64 * 64];  // Q staging, then P
  const int tid = threadIdx.x;
  const int wid = tid >> 6, lane = tid & 63;
  const int fr = lane & 15, kgv = lane >> 4;
  const size_t base = (size_t)bb * T_ * D_ + (size_t)hh * DH_;
  const unsigned short* qgp = (const unsigned short*)qg;
  const unsigned short* kgp = (const unsigned short*)kg;
  const unsigned short* vgp = (const unsigned short*)vg;
  const float C = 0.125f * 1.4426950408889634f;  // scale * log2(e)

  // ---- stage Q into Ps (pre-swizzled source -> linear LDS dest) ----
  {
    const int r8 = lane >> 3, cp = lane & 7;
#pragma unroll
    for (int u = 0; u < 2; ++u) {
      const int row = wid * 16 + u * 8 + r8;
      const int c16 = cp ^ (row & 7);
      g2l16((char*)Ps + (wid * 16 + u * 8) * 128,
            qgp + base + (size_t)(qb * 64 + row) * D_ + c16 * 8);
    }
  }
  asm volatile("s_waitcnt vmcnt(0)" ::: "memory");
  __syncthreads();
  s16x8 qf[2];
  {
    const int row = wid * 16 + fr;
    const char* rp = (const char*)Ps + row * 128;
    qf[0] = *reinterpret_cast<const s16x8*>(rp + (((0 + kgv) ^ (row & 7)) << 4));
    qf[1] = *reinterpret_cast<const s16x8*>(rp + (((4 + kgv) ^ (row & 7)) << 4));
  }

  f32x4 acco[4] = {};
  float m_run[4] = {-INFINITY, -INFINITY, -INFINITY, -INFINITY};
  float l_run[4] = {};

  for (int kb = 0; kb <= qb; ++kb) {
    __syncthreads();  // previous iteration's readers of Ks/Vt done; Q-frag reads done
    // ---- stage K ----
    {
      const int r8 = lane >> 3, cp = lane & 7;
#pragma unroll
      for (int u = 0; u < 2; ++u) {
        const int row = wid * 16 + u * 8 + r8;
        const int c16 = cp ^ (row & 7);
        g2l16((char*)Ks + (wid * 16 + u * 8) * 128,
              kgp + base + (size_t)(kb * 64 + row) * D_ + c16 * 8);
      }
    }
    // ---- stage V transposed (reg -> swizzled LDS, rotated write order) ----
    {
      const int kv0 = tid >> 3;
      const int d0 = (tid & 7) * 8;
      const int rot = tid & 7;
#pragma unroll
      for (int u = 0; u < 2; ++u) {
        const int kv = u * 32 + kv0;
        s16x8 sv = *reinterpret_cast<const s16x8*>(
            vgp + base + (size_t)(kb * 64 + kv) * D_ + d0);
#pragma unroll
        for (int j = 0; j < 8; ++j) {
          const int jj = (j + rot) & 7;
          const int d = d0 + jj;
          *(short*)((char*)Vt + d * 128 + ((((kv >> 3) ^ jj) & 7) << 4) + (kv & 7) * 2) = sv[jj];
        }
      }
    }
    asm volatile("s_waitcnt vmcnt(0)" ::: "memory");
    __syncthreads();

    // ---- QK^T: wave strip [16 q x 64 k] ----
    f32x4 accs[4] = {};
#pragma unroll
    for (int n = 0; n < 4; ++n) {
      const int row = n * 16 + fr;
      const char* rp = (const char*)Ks + row * 128;
      s16x8 kf0 = *reinterpret_cast<const s16x8*>(rp + (((0 + kgv) ^ (row & 7)) << 4));
      s16x8 kf1 = *reinterpret_cast<const s16x8*>(rp + (((4 + kgv) ^ (row & 7)) << 4));
      accs[n] = __builtin_amdgcn_mfma_f32_16x16x32_bf16(qf[0], kf0, accs[n], 0, 0, 0);
      accs[n] = __builtin_amdgcn_mfma_f32_16x16x32_bf16(qf[1], kf1, accs[n], 0, 0, 0);
    }

    // ---- online softmax (lane holds s[n][j]; row=wid*16+kgv*4+j, col=n*16+fr) ----
    const bool diag = (kb == qb);
    float mloc[4];
#pragma unroll
    for (int j = 0; j < 4; ++j) {
      float mm = -3.0e38f;
#pragma unroll
      for (int n = 0; n < 4; ++n)
        if (!(diag && n > wid)) mm = fmaxf(mm, accs[n][j]);
      mloc[j] = mm;
    }
#pragma unroll
    for (int off = 1; off < 16; off <<= 1)
#pragma unroll
      for (int j = 0; j < 4; ++j) mloc[j] = fmaxf(mloc[j], __shfl_xor(mloc[j], off));
    float aj[4];
#pragma unroll
    for (int j = 0; j < 4; ++j) {
      const float mn = fmaxf(m_run[j], mloc[j]);
      aj[j] = EXP2F((m_run[j] - mn) * C);
      m_run[j] = mn;
    }
    float psum[4] = {};
    unsigned short pb[4][4];
#pragma unroll
    for (int n = 0; n < 4; ++n) {
      const bool dead = diag && (n > wid);
#pragma unroll
      for (int j = 0; j < 4; ++j) {
        float p = dead ? 0.0f : EXP2F((accs[n][j] - m_run[j]) * C);
        psum[j] += p;
        pb[n][j] = f2b(p);
      }
    }
#pragma unroll
    for (int j = 0; j < 4; ++j) l_run[j] = l_run[j] * aj[j] + psum[j];
#pragma unroll
    for (int dt = 0; dt < 4; ++dt)
#pragma unroll
      for (int j = 0; j < 4; ++j) acco[dt][j] *= aj[j];
    // ---- write P (bf16, swizzled) ----
#pragma unroll
    for (int n = 0; n < 4; ++n) {
      const int c16b = n * 2 + (fr >> 3);
#pragma unroll
      for (int j = 0; j < 4; ++j) {
        const int row = wid * 16 + kgv * 4 + j;
        *(short*)((char*)Ps + row * 128 + (((c16b ^ (row & 7)) & 7) << 4) + (fr & 7) * 2) =
            (short)pb[n][j];
      }
    }
    // ---- PV: A=P rows (own wave's strip, intra-wave ordered), B=Vt rows ----
#pragma unroll
    for (int kk = 0; kk < 2; ++kk) {
      const int prow = wid * 16 + fr;
      s16x8 pf = *reinterpret_cast<const s16x8*>(
          (const char*)Ps + prow * 128 + ((((kk * 4 + kgv) ^ (prow & 7)) & 7) << 4));
#pragma unroll
      for (int dt = 0; dt < 4; ++dt) {
        const int vrow = dt * 16 + fr;
        s16x8 vf = *reinterpret_cast<const s16x8*>(
            (const char*)Vt + vrow * 128 + ((((kk * 4 + kgv) ^ (vrow & 7)) & 7) << 4));
        acco[dt] = __builtin_amdgcn_mfma_f32_16x16x32_bf16(pf, vf, acco[dt], 0, 0, 0);
      }
    }
  }

  // ---- epilogue: reduce l over fr group, normalize, store ----
#pragma unroll
  for (int off = 1; off < 16; off <<= 1)
#pragma unroll
    for (int j = 0; j < 4; ++j) l_run[j] += __shfl_xor(l_run[j], off);
  float inv[4];
#pragma unroll
  for (int j = 0; j < 4; ++j) inv[j] = 1.0f / l_run[j];
  unsigned short* yp = (unsigned short*)yg;
#pragma unroll
  for (int dt = 0; dt < 4; ++dt)
#pragma unroll
    for (int j = 0; j < 4; ++j) {
      const int row = qb * 64 + wid * 16 + kgv * 4 + j;
      yp[base + (size_t)row * D_ + dt * 16 + fr] = f2b(acco[dt][j] * inv[j]);
    }
}

extern "C" void kernel_launch(void* const* d_in, const int* in_sizes, int n_in,
                              void* d_out, int out_size, void* d_ws, size_t ws_size,
                              hipStream_t stream) {
  (void)in_sizes; (void)n_in; (void)out_size;
  const float* seq  = (const float*)d_in[0];
  const float* Wq   = (const float*)d_in[1];
  const float* bq   = (const float*)d_in[2];
  const float* Wk   = (const float*)d_in[3];
  const float* bk   = (const float*)d_in[4];
  const float* Wv   = (const float*)d_in[5];
  const float* bv   = (const float*)d_in[6];
  const float* Wp   = (const float*)d_in[7];
  const float* bp   = (const float*)d_in[8];
  const float* ln1g = (const float*)d_in[9];
  const float* ln1b = (const float*)d_in[10];
  const float* ln2g = (const float*)d_in[11];
  const float* ln2b = (const float*)d_in[12];
  const float* W1   = (const float*)d_in[13];
  const float* b1   = (const float*)d_in[14];
  const float* W2   = (const float*)d_in[15];
  const float* b2   = (const float*)d_in[16];
  const float* lnfg = (const float*)d_in[17];
  const float* lnfb = (const float*)d_in[18];

  float* x = (float*)d_out;
  char* ws = (char*)d_ws;
  const size_t MB = 1024ull * 1024ull;
  typedef __hip_bfloat16 bf16;
  bf16* wtq  = (bf16*)(ws + 0 * MB);
  bf16* wtk  = (bf16*)(ws + 2 * MB);
  bf16* wtv  = (bf16*)(ws + 4 * MB);
  bf16* wtp  = (bf16*)(ws + 6 * MB);
  bf16* wtF1 = (bf16*)(ws + 8 * MB);
  bf16* wtF2 = (bf16*)(ws + 16 * MB);
  bf16* hb   = (bf16*)(ws + 24 * MB);
  bf16* qb_  = (bf16*)(ws + 32 * MB);
  bf16* kb_  = (bf16*)(ws + 40 * MB);
  bf16* vb_  = (bf16*)(ws + 48 * MB);
  bf16* mid  = (bf16*)(ws + 56 * MB);
  const int CS = (ws_size >= 92 * MB) ? 4096 : 1024;
  const int NC = 4096 / CS;

  hipMemcpyAsync(x, seq, (size_t)M_ * D_ * sizeof(float), hipMemcpyDeviceToDevice, stream);

  const dim3 blk(256);
  for (int i = 0; i < 8; ++i) {
    const size_t wo  = (size_t)i * D_ * D_;
    const size_t vo  = (size_t)i * D_;
    const size_t w1o = (size_t)i * D_ * 4 * D_;

    ln_kernel<true><<<M_, blk, 0, stream>>>(x, hb, ln1g + vo, ln1b + vo);
    TPack tp;
    tp.s[0] = Wq + wo; tp.s[1] = Wk + wo; tp.s[2] = Wv + wo; tp.s[3] = Wp + wo;
    tp.d[0] = wtq; tp.d[1] = wtk; tp.d[2] = wtv; tp.d[3] = wtp;
    transpose4<<<dim3(32, 32, 4), blk, 0, stream>>>(tp);
    gemm_mfma<0><<<dim3(8, 32), blk, 0, stream>>>(hb, wtq, bq + vo, qb_, 1024, 1024);
    gemm_mfma<0><<<dim3(8, 32), blk, 0, stream>>>(hb, wtk, bk + vo, kb_, 1024, 1024);
    gemm_mfma<0><<<dim3(8, 32), blk, 0, stream>>>(hb, wtv, bv + vo, vb_, 1024, 1024);
    attn_mfma<<<dim3(16, 16, 4), blk, 0, stream>>>(qb_, kb_, vb_, hb);
    gemm_mfma<1><<<dim3(8, 32), blk, 0, stream>>>(hb, wtp, bp + vo, x, 1024, 1024);
    ln_kernel<true><<<M_, blk, 0, stream>>>(x, hb, ln2g + vo, ln2b + vo);
    for (int c = 0; c < NC; ++c) {
      transpose1<<<dim3(32, CS / 32), blk, 0, stream>>>(W1 + w1o + c * CS, 4096, wtF1, 1024);
      gemm_mfma<2><<<dim3(CS / 128, 32), blk, 0, stream>>>(
          hb, wtF1, b1 + (size_t)i * 4096 + c * CS, mid, CS, 1024);
      transpose1<<<dim3(CS / 32, 32), blk, 0, stream>>>(W2 + w1o + (size_t)c * CS * 1024, 1024, wtF2, CS);
      gemm_mfma<1><<<dim3(8, 32), blk, 0, stream>>>(
          mid, wtF2, (c == 0 ? b2 + vo : nullptr), x, 1024, CS);
    }
  }
  ln_kernel<false><<<M_, blk, 0, stream>>>(x, x, lnfg, lnfb);
}

// Round 4
// 2441.161 us; speedup vs baseline: 10.2604x; 1.2334x over previous
//
#include <hip/hip_runtime.h>
#include <hip/hip_bf16.h>
#include <math.h>

#define B_ 4
#define T_ 1024
#define D_ 1024
#define H_ 16
#define DH_ 64
#define M_ 4096
#define QSTR_ 3072   // fused qkv row stride
#define EPS_ 1e-5f

typedef __attribute__((ext_vector_type(4))) float f32x4;
typedef __attribute__((ext_vector_type(8))) short s16x8;

#if __has_builtin(__builtin_amdgcn_exp2f)
#define EXP2F __builtin_amdgcn_exp2f
#else
#define EXP2F exp2f
#endif

__device__ __forceinline__ float gelu_f(float x) {
  return 0.5f * x * (1.0f + erff(x * 0.70710678118654752f));
}
__device__ __forceinline__ float b2f(unsigned short u) {
  union { unsigned int i; float f; } c; c.i = ((unsigned int)u) << 16; return c.f;
}
__device__ __forceinline__ unsigned short f2b(float f) {
  __hip_bfloat16 h = __float2bfloat16(f);
  return *reinterpret_cast<unsigned short*>(&h);
}
__device__ __forceinline__ void g2l16(void* l, const void* g) {
  __builtin_amdgcn_global_load_lds(
      (const __attribute__((address_space(1))) void*)g,
      (__attribute__((address_space(3))) void*)l, 16, 0, 0);
}

// ---------------- LayerNorm ----------------
template<bool BF16OUT>
__global__ __launch_bounds__(256) void ln_kernel(
    const float* __restrict__ in, void* __restrict__ out,
    const float* __restrict__ g, const float* __restrict__ b) {
  const int row = blockIdx.x;
  const int tid = threadIdx.x;
  const float* rp = in + (size_t)row * D_;
  float4 v = *reinterpret_cast<const float4*>(rp + tid * 4);
  float s = v.x + v.y + v.z + v.w;
  float s2 = v.x * v.x + v.y * v.y + v.z * v.z + v.w * v.w;
#pragma unroll
  for (int off = 1; off < 64; off <<= 1) {
    s += __shfl_xor(s, off);
    s2 += __shfl_xor(s2, off);
  }
  __shared__ float red[2][4];
  const int wid = tid >> 6;
  if ((tid & 63) == 0) { red[0][wid] = s; red[1][wid] = s2; }
  __syncthreads();
  s = red[0][0] + red[0][1] + red[0][2] + red[0][3];
  s2 = red[1][0] + red[1][1] + red[1][2] + red[1][3];
  const float mu = s * (1.0f / D_);
  const float var = s2 * (1.0f / D_) - mu * mu;
  const float rs = rsqrtf(var + EPS_);
  float4 gv = *reinterpret_cast<const float4*>(g + tid * 4);
  float4 bv = *reinterpret_cast<const float4*>(b + tid * 4);
  float o0 = (v.x - mu) * rs * gv.x + bv.x;
  float o1 = (v.y - mu) * rs * gv.y + bv.y;
  float o2 = (v.z - mu) * rs * gv.z + bv.z;
  float o3 = (v.w - mu) * rs * gv.w + bv.w;
  if (BF16OUT) {
    ushort4 pk;
    pk.x = f2b(o0); pk.y = f2b(o1); pk.z = f2b(o2); pk.w = f2b(o3);
    *reinterpret_cast<ushort4*>((unsigned short*)out + (size_t)row * D_ + tid * 4) = pk;
  } else {
    *reinterpret_cast<float4*>((float*)out + (size_t)row * D_ + tid * 4) =
        make_float4(o0, o1, o2, o3);
  }
}

// ---------------- bias concat: [L][3072] <- bq|bk|bv ----------------
__global__ __launch_bounds__(256) void concat_bias(
    const float* __restrict__ bq, const float* __restrict__ bk,
    const float* __restrict__ bv, float* __restrict__ out) {
  const int i = blockIdx.x * 256 + threadIdx.x;   // 8*3072
  const int l = i / QSTR_, c = i % QSTR_;
  const float* src = (c < 1024) ? bq : ((c < 2048) ? bk : bv);
  out[i] = src[l * 1024 + (c & 1023)];
}

// ---------------- transpose fp32 [K][N] -> bf16 [N][K] ----------------
__device__ __forceinline__ void transpose_tile(
    const float* __restrict__ src, int sld,
    __hip_bfloat16* __restrict__ dst, int dld, int k0, int n0) {
  __shared__ float tile[32][33];
  const int t = threadIdx.x;
  const int r = t >> 3;
  const int cq = (t & 7) * 4;
  float4 vv = *reinterpret_cast<const float4*>(src + (size_t)(k0 + r) * sld + n0 + cq);
  tile[r][cq + 0] = vv.x; tile[r][cq + 1] = vv.y;
  tile[r][cq + 2] = vv.z; tile[r][cq + 3] = vv.w;
  __syncthreads();
  ushort4 o;
  o.x = f2b(tile[cq + 0][r]); o.y = f2b(tile[cq + 1][r]);
  o.z = f2b(tile[cq + 2][r]); o.w = f2b(tile[cq + 3][r]);
  *reinterpret_cast<ushort4*>((unsigned short*)dst + (size_t)(n0 + r) * dld + k0 + cq) = o;
}

struct TPack { const float* s[4]; __hip_bfloat16* d[4]; };

__global__ __launch_bounds__(256) void transpose4(TPack p) {
  transpose_tile(p.s[blockIdx.z], 1024, p.d[blockIdx.z], 1024,
                 blockIdx.x * 32, blockIdx.y * 32);
}
__global__ __launch_bounds__(256) void transpose1(
    const float* __restrict__ src, int sld,
    __hip_bfloat16* __restrict__ dst, int dld) {
  transpose_tile(src, sld, dst, dld, blockIdx.x * 32, blockIdx.y * 32);
}

// ---------------- bf16 MFMA GEMM, double-buffered prefetch + XCD swizzle ----------------
// C[BMxBN tile] = A[M,K] @ Bt[N,K]^T + bias.  BM=128.  BN in {128, 64}.
// MODE 0: store bf16; MODE 1: fp32 C += result; MODE 2: store bf16 gelu(result)
template<int MODE, int BN>
__global__ __launch_bounds__(256) void gemm_mfma(
    const __hip_bfloat16* __restrict__ A,
    const __hip_bfloat16* __restrict__ Bt,
    const float* __restrict__ bias,
    void* __restrict__ Cout, int N, int K) {
  __shared__ short As[2][128 * 32];
  __shared__ short Bs[2][BN * 32];
  // XCD-chunked swizzle (grids are multiples of 8 -> bijective)
  int bid = blockIdx.y * gridDim.x + blockIdx.x;
  const int nwg = gridDim.x * gridDim.y;
  bid = (bid & 7) * (nwg >> 3) + (bid >> 3);
  const int gn = (bid % gridDim.x) * BN;
  const int gm = (bid / gridDim.x) * 128;

  const int tid = threadIdx.x;
  const int wid = tid >> 6, lane = tid & 63;
  constexpr int MR = (BN == 128) ? 4 : 2;
  const int wm = (BN == 128) ? (wid >> 1) : wid;
  const int wn = (BN == 128) ? (wid & 1) : 0;
  const int fr = lane & 15, kg = lane >> 4;

  const int ldr = lane >> 2;            // staging row within 16-row group
  const int ldk = (lane & 3) * 8;       // staging k offset
  const unsigned short* ap =
      (const unsigned short*)A + (size_t)(gm + wid * 32 + ldr) * K + ldk;
  const unsigned short* bp =
      (const unsigned short*)Bt +
      (size_t)(gn + ((BN == 128) ? wid * 32 : wid * 16) + ldr) * K + ldk;

  // prologue: stage k-tile 0 into buf 0
  {
    g2l16((char*)As[0] + (wid * 2) * 1024, ap);
    g2l16((char*)As[0] + (wid * 2 + 1) * 1024, ap + (size_t)16 * K);
    if (BN == 128) {
      g2l16((char*)Bs[0] + (wid * 2) * 1024, bp);
      g2l16((char*)Bs[0] + (wid * 2 + 1) * 1024, bp + (size_t)16 * K);
    } else {
      g2l16((char*)Bs[0] + wid * 1024, bp);
    }
    ap += 32; bp += 32;
  }
  asm volatile("s_waitcnt vmcnt(0)" ::: "memory");
  __syncthreads();

  f32x4 acc[MR][4] = {};
  int cur = 0;
  for (int kt = 0; kt < K; kt += 32) {
    if (kt + 32 < K) {  // prefetch next k-tile into other buffer
      g2l16((char*)As[cur ^ 1] + (wid * 2) * 1024, ap);
      g2l16((char*)As[cur ^ 1] + (wid * 2 + 1) * 1024, ap + (size_t)16 * K);
      if (BN == 128) {
        g2l16((char*)Bs[cur ^ 1] + (wid * 2) * 1024, bp);
        g2l16((char*)Bs[cur ^ 1] + (wid * 2 + 1) * 1024, bp + (size_t)16 * K);
      } else {
        g2l16((char*)Bs[cur ^ 1] + wid * 1024, bp);
      }
      ap += 32; bp += 32;
    }
    s16x8 af[MR], bfr[4];
#pragma unroll
    for (int m = 0; m < MR; ++m)
      af[m] = *reinterpret_cast<const s16x8*>(
          &As[cur][(wm * (16 * MR) + m * 16 + fr) * 32 + kg * 8]);
#pragma unroll
    for (int n = 0; n < 4; ++n)
      bfr[n] = *reinterpret_cast<const s16x8*>(
          &Bs[cur][(wn * 64 + n * 16 + fr) * 32 + kg * 8]);
#pragma unroll
    for (int m = 0; m < MR; ++m)
#pragma unroll
      for (int n = 0; n < 4; ++n)
        acc[m][n] = __builtin_amdgcn_mfma_f32_16x16x32_bf16(af[m], bfr[n], acc[m][n], 0, 0, 0);
    asm volatile("s_waitcnt vmcnt(0)" ::: "memory");
    __syncthreads();
    cur ^= 1;
  }

  const int r0 = gm + wm * (16 * MR);
  const int c0 = gn + wn * 64;
  float bb[4];
#pragma unroll
  for (int n = 0; n < 4; ++n)
    bb[n] = bias ? bias[c0 + n * 16 + fr] : 0.0f;
#pragma unroll
  for (int m = 0; m < MR; ++m) {
#pragma unroll
    for (int j = 0; j < 4; ++j) {
      const int row = r0 + m * 16 + kg * 4 + j;
#pragma unroll
      for (int n = 0; n < 4; ++n) {
        float val = acc[m][n][j] + bb[n];
        const size_t idx = (size_t)row * N + c0 + n * 16 + fr;
        if (MODE == 0) {
          ((unsigned short*)Cout)[idx] = f2b(val);
        } else if (MODE == 1) {
          float* cp = (float*)Cout + idx;
          *cp = *cp + val;
        } else {
          ((unsigned short*)Cout)[idx] = f2b(gelu_f(val));
        }
      }
    }
  }
}

// ---------------- MFMA flash attention, block-causal ----------------
// reads fused qkv [4096][3072]; writes y [4096][1024]
__global__ __launch_bounds__(256) void attn_mfma(
    const __hip_bfloat16* __restrict__ qkv, __hip_bfloat16* __restrict__ yg) {
  const int qb = 15 - blockIdx.x;
  const int hh = blockIdx.y;
  const int bb = blockIdx.z;
  __shared__ short Ks[64 * 64];
  __shared__ short Vt[64 * 64];
  __shared__ short Ps[64 * 64];
  const int tid = threadIdx.x;
  const int wid = tid >> 6, lane = tid & 63;
  const int fr = lane & 15, kgv = lane >> 4;
  const size_t qb_base = (size_t)bb * T_ * QSTR_ + (size_t)hh * DH_;
  const unsigned short* qgp = (const unsigned short*)qkv + qb_base;
  const unsigned short* kgp = (const unsigned short*)qkv + qb_base + 1024;
  const unsigned short* vgp = (const unsigned short*)qkv + qb_base + 2048;
  const float C = 0.125f * 1.4426950408889634f;

  // stage Q (pre-swizzled source -> linear LDS dest)
  {
    const int r8 = lane >> 3, cp = lane & 7;
#pragma unroll
    for (int u = 0; u < 2; ++u) {
      const int row = wid * 16 + u * 8 + r8;
      const int c16 = cp ^ (row & 7);
      g2l16((char*)Ps + (wid * 16 + u * 8) * 128,
            qgp + (size_t)(qb * 64 + row) * QSTR_ + c16 * 8);
    }
  }
  asm volatile("s_waitcnt vmcnt(0)" ::: "memory");
  __syncthreads();
  s16x8 qf[2];
  {
    const int row = wid * 16 + fr;
    const char* rp = (const char*)Ps + row * 128;
    qf[0] = *reinterpret_cast<const s16x8*>(rp + (((0 + kgv) ^ (row & 7)) << 4));
    qf[1] = *reinterpret_cast<const s16x8*>(rp + (((4 + kgv) ^ (row & 7)) << 4));
  }

  f32x4 acco[4] = {};
  float m_run[4] = {-INFINITY, -INFINITY, -INFINITY, -INFINITY};
  float l_run[4] = {};

  for (int kb = 0; kb <= qb; ++kb) {
    __syncthreads();
    // stage K
    {
      const int r8 = lane >> 3, cp = lane & 7;
#pragma unroll
      for (int u = 0; u < 2; ++u) {
        const int row = wid * 16 + u * 8 + r8;
        const int c16 = cp ^ (row & 7);
        g2l16((char*)Ks + (wid * 16 + u * 8) * 128,
              kgp + (size_t)(kb * 64 + row) * QSTR_ + c16 * 8);
      }
    }
    // stage V transposed (reg -> swizzled LDS)
    {
      const int kv0 = tid >> 3;
      const int d0 = (tid & 7) * 8;
      const int rot = tid & 7;
#pragma unroll
      for (int u = 0; u < 2; ++u) {
        const int kv = u * 32 + kv0;
        s16x8 sv = *reinterpret_cast<const s16x8*>(
            vgp + (size_t)(kb * 64 + kv) * QSTR_ + d0);
#pragma unroll
        for (int j = 0; j < 8; ++j) {
          const int jj = (j + rot) & 7;
          const int d = d0 + jj;
          *(short*)((char*)Vt + d * 128 + ((((kv >> 3) ^ jj) & 7) << 4) + (kv & 7) * 2) = sv[jj];
        }
      }
    }
    asm volatile("s_waitcnt vmcnt(0)" ::: "memory");
    __syncthreads();

    // QK^T
    f32x4 accs[4] = {};
#pragma unroll
    for (int n = 0; n < 4; ++n) {
      const int row = n * 16 + fr;
      const char* rp = (const char*)Ks + row * 128;
      s16x8 kf0 = *reinterpret_cast<const s16x8*>(rp + (((0 + kgv) ^ (row & 7)) << 4));
      s16x8 kf1 = *reinterpret_cast<const s16x8*>(rp + (((4 + kgv) ^ (row & 7)) << 4));
      accs[n] = __builtin_amdgcn_mfma_f32_16x16x32_bf16(qf[0], kf0, accs[n], 0, 0, 0);
      accs[n] = __builtin_amdgcn_mfma_f32_16x16x32_bf16(qf[1], kf1, accs[n], 0, 0, 0);
    }

    // online softmax
    const bool diag = (kb == qb);
    float mloc[4];
#pragma unroll
    for (int j = 0; j < 4; ++j) {
      float mm = -3.0e38f;
#pragma unroll
      for (int n = 0; n < 4; ++n)
        if (!(diag && n > wid)) mm = fmaxf(mm, accs[n][j]);
      mloc[j] = mm;
    }
#pragma unroll
    for (int off = 1; off < 16; off <<= 1)
#pragma unroll
      for (int j = 0; j < 4; ++j) mloc[j] = fmaxf(mloc[j], __shfl_xor(mloc[j], off));
    float aj[4];
#pragma unroll
    for (int j = 0; j < 4; ++j) {
      const float mn = fmaxf(m_run[j], mloc[j]);
      aj[j] = EXP2F((m_run[j] - mn) * C);
      m_run[j] = mn;
    }
    float psum[4] = {};
    unsigned short pb[4][4];
#pragma unroll
    for (int n = 0; n < 4; ++n) {
      const bool dead = diag && (n > wid);
#pragma unroll
      for (int j = 0; j < 4; ++j) {
        float p = dead ? 0.0f : EXP2F((accs[n][j] - m_run[j]) * C);
        psum[j] += p;
        pb[n][j] = f2b(p);
      }
    }
#pragma unroll
    for (int j = 0; j < 4; ++j) l_run[j] = l_run[j] * aj[j] + psum[j];
#pragma unroll
    for (int dt = 0; dt < 4; ++dt)
#pragma unroll
      for (int j = 0; j < 4; ++j) acco[dt][j] *= aj[j];
    // write P (bf16, swizzled)
#pragma unroll
    for (int n = 0; n < 4; ++n) {
      const int c16b = n * 2 + (fr >> 3);
#pragma unroll
      for (int j = 0; j < 4; ++j) {
        const int row = wid * 16 + kgv * 4 + j;
        *(short*)((char*)Ps + row * 128 + (((c16b ^ (row & 7)) & 7) << 4) + (fr & 7) * 2) =
            (short)pb[n][j];
      }
    }
    // PV
#pragma unroll
    for (int kk = 0; kk < 2; ++kk) {
      const int prow = wid * 16 + fr;
      s16x8 pf = *reinterpret_cast<const s16x8*>(
          (const char*)Ps + prow * 128 + ((((kk * 4 + kgv) ^ (prow & 7)) & 7) << 4));
#pragma unroll
      for (int dt = 0; dt < 4; ++dt) {
        const int vrow = dt * 16 + fr;
        s16x8 vf = *reinterpret_cast<const s16x8*>(
            (const char*)Vt + vrow * 128 + ((((kk * 4 + kgv) ^ (vrow & 7)) & 7) << 4));
        acco[dt] = __builtin_amdgcn_mfma_f32_16x16x32_bf16(pf, vf, acco[dt], 0, 0, 0);
      }
    }
  }

  // epilogue
#pragma unroll
  for (int off = 1; off < 16; off <<= 1)
#pragma unroll
    for (int j = 0; j < 4; ++j) l_run[j] += __shfl_xor(l_run[j], off);
  float inv[4];
#pragma unroll
  for (int j = 0; j < 4; ++j) inv[j] = 1.0f / l_run[j];
  unsigned short* yp = (unsigned short*)yg + (size_t)bb * T_ * D_ + (size_t)hh * DH_;
#pragma unroll
  for (int dt = 0; dt < 4; ++dt)
#pragma unroll
    for (int j = 0; j < 4; ++j) {
      const int row = qb * 64 + wid * 16 + kgv * 4 + j;
      yp[(size_t)row * D_ + dt * 16 + fr] = f2b(acco[dt][j] * inv[j]);
    }
}

extern "C" void kernel_launch(void* const* d_in, const int* in_sizes, int n_in,
                              void* d_out, int out_size, void* d_ws, size_t ws_size,
                              hipStream_t stream) {
  (void)in_sizes; (void)n_in; (void)out_size; (void)ws_size;
  const float* seq  = (const float*)d_in[0];
  const float* Wq   = (const float*)d_in[1];
  const float* bq   = (const float*)d_in[2];
  const float* Wk   = (const float*)d_in[3];
  const float* bk   = (const float*)d_in[4];
  const float* Wv   = (const float*)d_in[5];
  const float* bv   = (const float*)d_in[6];
  const float* Wp   = (const float*)d_in[7];
  const float* bp   = (const float*)d_in[8];
  const float* ln1g = (const float*)d_in[9];
  const float* ln1b = (const float*)d_in[10];
  const float* ln2g = (const float*)d_in[11];
  const float* ln2b = (const float*)d_in[12];
  const float* W1   = (const float*)d_in[13];
  const float* b1   = (const float*)d_in[14];
  const float* W2   = (const float*)d_in[15];
  const float* b2   = (const float*)d_in[16];
  const float* lnfg = (const float*)d_in[17];
  const float* lnfb = (const float*)d_in[18];

  float* x = (float*)d_out;
  char* ws = (char*)d_ws;
  const size_t MB = 1024ull * 1024ull;
  typedef __hip_bfloat16 bf16;
  bf16*  wtqkv = (bf16*)(ws + 0 * MB);    // [3072][1024]
  bf16*  wtp   = (bf16*)(ws + 6 * MB);    // [1024][1024]
  bf16*  wtF1  = (bf16*)(ws + 8 * MB);    // [4096][1024]
  bf16*  wtF2  = (bf16*)(ws + 16 * MB);   // [1024][4096]
  bf16*  hb    = (bf16*)(ws + 24 * MB);   // [4096][1024]
  bf16*  qkv   = (bf16*)(ws + 32 * MB);   // [4096][3072]
  bf16*  mid   = (bf16*)(ws + 56 * MB);   // [4096][4096]
  float* bqkv  = (float*)(ws + 88 * MB);  // [8][3072]

  hipMemcpyAsync(x, seq, (size_t)M_ * D_ * sizeof(float), hipMemcpyDeviceToDevice, stream);

  const dim3 blk(256);
  concat_bias<<<96, blk, 0, stream>>>(bq, bk, bv, bqkv);

  for (int i = 0; i < 8; ++i) {
    const size_t wo  = (size_t)i * D_ * D_;
    const size_t vo  = (size_t)i * D_;
    const size_t w1o = (size_t)i * D_ * 4 * D_;

    ln_kernel<true><<<M_, blk, 0, stream>>>(x, hb, ln1g + vo, ln1b + vo);
    TPack tp;
    tp.s[0] = Wq + wo; tp.s[1] = Wk + wo; tp.s[2] = Wv + wo; tp.s[3] = Wp + wo;
    tp.d[0] = wtqkv; tp.d[1] = wtqkv + 1024 * 1024; tp.d[2] = wtqkv + 2048 * 1024;
    tp.d[3] = wtp;
    transpose4<<<dim3(32, 32, 4), blk, 0, stream>>>(tp);
    // fused QKV: N=3072, 768 blocks
    gemm_mfma<0, 128><<<dim3(24, 32), blk, 0, stream>>>(
        hb, wtqkv, bqkv + (size_t)i * QSTR_, qkv, QSTR_, 1024);
    attn_mfma<<<dim3(16, 16, 4), blk, 0, stream>>>(qkv, hb);
    // proj: N=1024, BN=64 -> 512 blocks
    gemm_mfma<1, 64><<<dim3(16, 32), blk, 0, stream>>>(hb, wtp, bp + vo, x, 1024, 1024);
    ln_kernel<true><<<M_, blk, 0, stream>>>(x, hb, ln2g + vo, ln2b + vo);
    // FFN up: N=4096, 1024 blocks
    transpose1<<<dim3(32, 128), blk, 0, stream>>>(W1 + w1o, 4096, wtF1, 1024);
    gemm_mfma<2, 128><<<dim3(32, 32), blk, 0, stream>>>(
        hb, wtF1, b1 + (size_t)i * 4096, mid, 4096, 1024);
    // FFN down: N=1024, K=4096, BN=64 -> 512 blocks
    transpose1<<<dim3(128, 32), blk, 0, stream>>>(W2 + w1o, 1024, wtF2, 4096);
    gemm_mfma<1, 64><<<dim3(16, 32), blk, 0, stream>>>(
        mid, wtF2, b2 + vo, x, 1024, 4096);
  }
  ln_kernel<false><<<M_, blk, 0, stream>>>(x, x, lnfg, lnfb);
}

// Round 6
// 2304.532 us; speedup vs baseline: 10.8687x; 1.0593x over previous
//
#include <hip/hip_runtime.h>
#include <hip/hip_bf16.h>
#include <math.h>

#define B_ 4
#define T_ 1024
#define D_ 1024
#define H_ 16
#define DH_ 64
#define M_ 4096
#define QSTR_ 3072   // fused qkv row stride
#define EPS_ 1e-5f

typedef __attribute__((ext_vector_type(4))) float f32x4;
typedef __attribute__((ext_vector_type(8))) short s16x8;

#if __has_builtin(__builtin_amdgcn_exp2f)
#define EXP2F __builtin_amdgcn_exp2f
#else
#define EXP2F exp2f
#endif

__device__ __forceinline__ float gelu_f(float x) {
  return 0.5f * x * (1.0f + erff(x * 0.70710678118654752f));
}
__device__ __forceinline__ float b2f(unsigned short u) {
  union { unsigned int i; float f; } c; c.i = ((unsigned int)u) << 16; return c.f;
}
__device__ __forceinline__ unsigned short f2b(float f) {
  __hip_bfloat16 h = __float2bfloat16(f);
  return *reinterpret_cast<unsigned short*>(&h);
}
__device__ __forceinline__ void g2l16(void* l, const void* g) {
  __builtin_amdgcn_global_load_lds(
      (const __attribute__((address_space(1))) void*)g,
      (__attribute__((address_space(3))) void*)l, 16, 0, 0);
}

// ---------------- LayerNorm ----------------
template<bool BF16OUT>
__global__ __launch_bounds__(256) void ln_kernel(
    const float* __restrict__ in, void* __restrict__ out,
    const float* __restrict__ g, const float* __restrict__ b) {
  const int row = blockIdx.x;
  const int tid = threadIdx.x;
  const float* rp = in + (size_t)row * D_;
  float4 v = *reinterpret_cast<const float4*>(rp + tid * 4);
  float s = v.x + v.y + v.z + v.w;
  float s2 = v.x * v.x + v.y * v.y + v.z * v.z + v.w * v.w;
#pragma unroll
  for (int off = 1; off < 64; off <<= 1) {
    s += __shfl_xor(s, off);
    s2 += __shfl_xor(s2, off);
  }
  __shared__ float red[2][4];
  const int wid = tid >> 6;
  if ((tid & 63) == 0) { red[0][wid] = s; red[1][wid] = s2; }
  __syncthreads();
  s = red[0][0] + red[0][1] + red[0][2] + red[0][3];
  s2 = red[1][0] + red[1][1] + red[1][2] + red[1][3];
  const float mu = s * (1.0f / D_);
  const float var = s2 * (1.0f / D_) - mu * mu;
  const float rs = rsqrtf(var + EPS_);
  float4 gv = *reinterpret_cast<const float4*>(g + tid * 4);
  float4 bv = *reinterpret_cast<const float4*>(b + tid * 4);
  float o0 = (v.x - mu) * rs * gv.x + bv.x;
  float o1 = (v.y - mu) * rs * gv.y + bv.y;
  float o2 = (v.z - mu) * rs * gv.z + bv.z;
  float o3 = (v.w - mu) * rs * gv.w + bv.w;
  if (BF16OUT) {
    ushort4 pk;
    pk.x = f2b(o0); pk.y = f2b(o1); pk.z = f2b(o2); pk.w = f2b(o3);
    *reinterpret_cast<ushort4*>((unsigned short*)out + (size_t)row * D_ + tid * 4) = pk;
  } else {
    *reinterpret_cast<float4*>((float*)out + (size_t)row * D_ + tid * 4) =
        make_float4(o0, o1, o2, o3);
  }
}

// ---------------- bias concat: [L][3072] <- bq|bk|bv ----------------
__global__ __launch_bounds__(256) void concat_bias(
    const float* __restrict__ bq, const float* __restrict__ bk,
    const float* __restrict__ bv, float* __restrict__ out) {
  const int i = blockIdx.x * 256 + threadIdx.x;
  const int l = i / QSTR_, c = i % QSTR_;
  const float* src = (c < 1024) ? bq : ((c < 2048) ? bk : bv);
  out[i] = src[l * 1024 + (c & 1023)];
}

// ---------------- all weight transposes for one layer, single launch ----------------
__device__ __forceinline__ void transpose_tile(
    const float* __restrict__ src, int sld,
    __hip_bfloat16* __restrict__ dst, int dld, int k0, int n0) {
  __shared__ float tile[32][33];
  const int t = threadIdx.x;
  const int r = t >> 3;
  const int cq = (t & 7) * 4;
  float4 vv = *reinterpret_cast<const float4*>(src + (size_t)(k0 + r) * sld + n0 + cq);
  tile[r][cq + 0] = vv.x; tile[r][cq + 1] = vv.y;
  tile[r][cq + 2] = vv.z; tile[r][cq + 3] = vv.w;
  __syncthreads();
  ushort4 o;
  o.x = f2b(tile[cq + 0][r]); o.y = f2b(tile[cq + 1][r]);
  o.z = f2b(tile[cq + 2][r]); o.w = f2b(tile[cq + 3][r]);
  *reinterpret_cast<ushort4*>((unsigned short*)dst + (size_t)(n0 + r) * dld + k0 + cq) = o;
}

struct TrAll {
  const float *wq, *wk, *wv, *wp, *w1, *w2;
  __hip_bfloat16 *dqkv, *dp, *d1, *d2;
};

__global__ __launch_bounds__(256) void transpose_all(TrAll a) {
  const int t = blockIdx.x;
  const float* src;
  __hip_bfloat16* dst;
  int sld, dld, k0, n0;
  if (t < 4096) {
    const int m = t >> 10, tile = t & 1023;
    k0 = (tile >> 5) * 32; n0 = (tile & 31) * 32;
    src = (m == 0) ? a.wq : (m == 1) ? a.wk : (m == 2) ? a.wv : a.wp;
    sld = 1024; dld = 1024;
    dst = (m < 3) ? (a.dqkv + (size_t)m * 1024 * 1024) : a.dp;
  } else if (t < 8192) {
    const int tile = t - 4096;
    k0 = (tile & 31) * 32; n0 = (tile >> 5) * 32;
    src = a.w1; sld = 4096; dst = a.d1; dld = 1024;
  } else {
    const int tile = t - 8192;
    k0 = (tile >> 5) * 32; n0 = (tile & 31) * 32;
    src = a.w2; sld = 1024; dst = a.d2; dld = 4096;
  }
  transpose_tile(src, sld, dst, dld, k0, n0);
}

// ---------------- bf16 MFMA GEMM, double-buffered prefetch + XCD swizzle ----------------
template<int MODE, int BN>
__global__ __launch_bounds__(256) void gemm_mfma(
    const __hip_bfloat16* __restrict__ A,
    const __hip_bfloat16* __restrict__ Bt,
    const float* __restrict__ bias,
    void* __restrict__ Cout, int N, int K) {
  __shared__ short As[2][128 * 32];
  __shared__ short Bs[2][BN * 32];
  int bid = blockIdx.y * gridDim.x + blockIdx.x;
  const int nwg = gridDim.x * gridDim.y;
  bid = (bid & 7) * (nwg >> 3) + (bid >> 3);
  const int gn = (bid % gridDim.x) * BN;
  const int gm = (bid / gridDim.x) * 128;

  const int tid = threadIdx.x;
  const int wid = tid >> 6, lane = tid & 63;
  constexpr int MR = (BN == 128) ? 4 : 2;
  const int wm = (BN == 128) ? (wid >> 1) : wid;
  const int wn = (BN == 128) ? (wid & 1) : 0;
  const int fr = lane & 15, kg = lane >> 4;

  const int ldr = lane >> 2;
  const int ldk = (lane & 3) * 8;
  const unsigned short* ap =
      (const unsigned short*)A + (size_t)(gm + wid * 32 + ldr) * K + ldk;
  const unsigned short* bp =
      (const unsigned short*)Bt +
      (size_t)(gn + ((BN == 128) ? wid * 32 : wid * 16) + ldr) * K + ldk;

  {
    g2l16((char*)As[0] + (wid * 2) * 1024, ap);
    g2l16((char*)As[0] + (wid * 2 + 1) * 1024, ap + (size_t)16 * K);
    if (BN == 128) {
      g2l16((char*)Bs[0] + (wid * 2) * 1024, bp);
      g2l16((char*)Bs[0] + (wid * 2 + 1) * 1024, bp + (size_t)16 * K);
    } else {
      g2l16((char*)Bs[0] + wid * 1024, bp);
    }
    ap += 32; bp += 32;
  }
  asm volatile("s_waitcnt vmcnt(0)" ::: "memory");
  __syncthreads();

  f32x4 acc[MR][4] = {};
  int cur = 0;
  for (int kt = 0; kt < K; kt += 32) {
    if (kt + 32 < K) {
      g2l16((char*)As[cur ^ 1] + (wid * 2) * 1024, ap);
      g2l16((char*)As[cur ^ 1] + (wid * 2 + 1) * 1024, ap + (size_t)16 * K);
      if (BN == 128) {
        g2l16((char*)Bs[cur ^ 1] + (wid * 2) * 1024, bp);
        g2l16((char*)Bs[cur ^ 1] + (wid * 2 + 1) * 1024, bp + (size_t)16 * K);
      } else {
        g2l16((char*)Bs[cur ^ 1] + wid * 1024, bp);
      }
      ap += 32; bp += 32;
    }
    s16x8 af[MR], bfr[4];
#pragma unroll
    for (int m = 0; m < MR; ++m)
      af[m] = *reinterpret_cast<const s16x8*>(
          &As[cur][(wm * (16 * MR) + m * 16 + fr) * 32 + kg * 8]);
#pragma unroll
    for (int n = 0; n < 4; ++n)
      bfr[n] = *reinterpret_cast<const s16x8*>(
          &Bs[cur][(wn * 64 + n * 16 + fr) * 32 + kg * 8]);
#pragma unroll
    for (int m = 0; m < MR; ++m)
#pragma unroll
      for (int n = 0; n < 4; ++n)
        acc[m][n] = __builtin_amdgcn_mfma_f32_16x16x32_bf16(af[m], bfr[n], acc[m][n], 0, 0, 0);
    asm volatile("s_waitcnt vmcnt(0)" ::: "memory");
    __syncthreads();
    cur ^= 1;
  }

  const int r0 = gm + wm * (16 * MR);
  const int c0 = gn + wn * 64;
  float bb[4];
#pragma unroll
  for (int n = 0; n < 4; ++n)
    bb[n] = bias ? bias[c0 + n * 16 + fr] : 0.0f;
#pragma unroll
  for (int m = 0; m < MR; ++m) {
#pragma unroll
    for (int j = 0; j < 4; ++j) {
      const int row = r0 + m * 16 + kg * 4 + j;
#pragma unroll
      for (int n = 0; n < 4; ++n) {
        float val = acc[m][n][j] + bb[n];
        const size_t idx = (size_t)row * N + c0 + n * 16 + fr;
        if (MODE == 0) {
          ((unsigned short*)Cout)[idx] = f2b(val);
        } else if (MODE == 1) {
          float* cp = (float*)Cout + idx;
          *cp = *cp + val;
        } else {
          ((unsigned short*)Cout)[idx] = f2b(gelu_f(val));
        }
      }
    }
  }
}

// ---------------- MFMA flash attention v3: QBLK=128, R4-proven inner paths ----------------
// grid (8,16,4). 4 waves; wave owns q rows [wid*32, wid*32+32) as 2 rg groups of 16.
// All 64-col bf16 LDS tiles swizzled: elem (r,c) at byte
//   r*128 + ((((c>>3) ^ (r&7)) & 7) << 4) + (c&7)*2
// Qs (16KB) staged then reused as P[128][64] (same swizzle).
__global__ __launch_bounds__(256) void attn_mfma(
    const __hip_bfloat16* __restrict__ qkv, __hip_bfloat16* __restrict__ yg) {
  const int qb = 7 - blockIdx.x;  // heavy first
  const int hh = blockIdx.y;
  const int bb = blockIdx.z;
  __shared__ short Qs[128 * 64];  // Q staging, then P
  __shared__ short Ks[64 * 64];
  __shared__ short Vt[64 * 64];   // V transposed: row=d, col=k (swizzled)
  const int tid = threadIdx.x;
  const int wid = tid >> 6, lane = tid & 63;
  const int fr = lane & 15, kg = lane >> 4;
  const size_t qb_base = (size_t)bb * T_ * QSTR_ + (size_t)hh * DH_;
  const unsigned short* qgp = (const unsigned short*)qkv + qb_base;
  const unsigned short* kgp = qgp + 1024;
  const unsigned short* vgp = qgp + 2048;
  const float C = 0.125f * 1.4426950408889634f;  // scale * log2(e)

  // ---- stage Q 128 rows (pre-swizzled source -> linear LDS) ----
  {
    const int r8 = lane >> 3, cp = lane & 7;
#pragma unroll
    for (int u = 0; u < 4; ++u) {
      const int row = wid * 32 + u * 8 + r8;
      const int c16 = cp ^ (row & 7);
      g2l16((char*)Qs + (wid * 32 + u * 8) * 128,
            qgp + (size_t)(qb * 128 + row) * QSTR_ + c16 * 8);
    }
  }
  asm volatile("s_waitcnt vmcnt(0)" ::: "memory");
  __syncthreads();
  s16x8 qf[2][2];
#pragma unroll
  for (int rg = 0; rg < 2; ++rg) {
    const int row = wid * 32 + rg * 16 + fr;
    const char* rp = (const char*)Qs + row * 128;
    qf[rg][0] = *reinterpret_cast<const s16x8*>(rp + (((0 + kg) ^ (row & 7)) << 4));
    qf[rg][1] = *reinterpret_cast<const s16x8*>(rp + (((4 + kg) ^ (row & 7)) << 4));
  }

  f32x4 acco[2][4] = {};
  float m_run[2][4], l_run[2][4];
#pragma unroll
  for (int rg = 0; rg < 2; ++rg)
#pragma unroll
    for (int j = 0; j < 4; ++j) { m_run[rg][j] = -INFINITY; l_run[rg][j] = 0.f; }

  const int q16hi = qb * 8 + wid * 2 + 1;
  const int ntile = 2 * qb + 2;
  for (int kt = 0; kt < ntile; ++kt) {
    __syncthreads();  // previous tile's readers done
    // ---- stage K (pre-swizzled source) ----
    {
      const int r8 = lane >> 3, cp = lane & 7;
#pragma unroll
      for (int u = 0; u < 2; ++u) {
        const int row = wid * 16 + u * 8 + r8;
        const int c16 = cp ^ (row & 7);
        g2l16((char*)Ks + (wid * 16 + u * 8) * 128,
              kgp + (size_t)(kt * 64 + row) * QSTR_ + c16 * 8);
      }
    }
    // ---- stage V transposed (reg -> swizzled LDS, rotated write order; R4-proven) ----
    {
      const int kv0 = tid >> 3;
      const int d0 = (tid & 7) * 8;
      const int rot = tid & 7;
#pragma unroll
      for (int u = 0; u < 2; ++u) {
        const int kv = u * 32 + kv0;
        s16x8 sv = *reinterpret_cast<const s16x8*>(
            vgp + (size_t)(kt * 64 + kv) * QSTR_ + d0);
#pragma unroll
        for (int j = 0; j < 8; ++j) {
          const int jj = (j + rot) & 7;
          const int d = d0 + jj;
          *(short*)((char*)Vt + d * 128 + ((((kv >> 3) ^ jj) & 7) << 4) + (kv & 7) * 2) = sv[jj];
        }
      }
    }
    asm volatile("s_waitcnt vmcnt(0)" ::: "memory");
    __syncthreads();

    if (kt * 4 <= q16hi) {
      // ---- QK^T: 16 MFMA ----
      f32x4 accs[2][4] = {};
#pragma unroll
      for (int n = 0; n < 4; ++n) {
        const int row = n * 16 + fr;
        const char* rp = (const char*)Ks + row * 128;
        s16x8 kf0 = *reinterpret_cast<const s16x8*>(rp + (((0 + kg) ^ (row & 7)) << 4));
        s16x8 kf1 = *reinterpret_cast<const s16x8*>(rp + (((4 + kg) ^ (row & 7)) << 4));
#pragma unroll
        for (int rg = 0; rg < 2; ++rg) {
          accs[rg][n] = __builtin_amdgcn_mfma_f32_16x16x32_bf16(qf[rg][0], kf0, accs[rg][n], 0, 0, 0);
          accs[rg][n] = __builtin_amdgcn_mfma_f32_16x16x32_bf16(qf[rg][1], kf1, accs[rg][n], 0, 0, 0);
        }
      }
      // ---- online softmax + P write (R4-proven scalar swizzled stores) ----
#pragma unroll
      for (int rg = 0; rg < 2; ++rg) {
        const int q16 = qb * 8 + wid * 2 + rg;
        float mloc[4] = {-3.0e38f, -3.0e38f, -3.0e38f, -3.0e38f};
#pragma unroll
        for (int n = 0; n < 4; ++n)
          if (kt * 4 + n <= q16)
#pragma unroll
            for (int j = 0; j < 4; ++j) mloc[j] = fmaxf(mloc[j], accs[rg][n][j]);
#pragma unroll
        for (int off = 1; off < 16; off <<= 1)
#pragma unroll
          for (int j = 0; j < 4; ++j) mloc[j] = fmaxf(mloc[j], __shfl_xor(mloc[j], off));
        float a_[4];
#pragma unroll
        for (int j = 0; j < 4; ++j) {
          const float mn = fmaxf(m_run[rg][j], mloc[j]);
          a_[j] = EXP2F((m_run[rg][j] - mn) * C);
          m_run[rg][j] = mn;
        }
        float psum[4] = {};
#pragma unroll
        for (int n = 0; n < 4; ++n) {
          const bool dead = (kt * 4 + n > q16);
          const int c16b = n * 2 + (fr >> 3);
#pragma unroll
          for (int j = 0; j < 4; ++j) {
            float p = dead ? 0.0f : EXP2F((accs[rg][n][j] - m_run[rg][j]) * C);
            psum[j] += p;
            const int row = wid * 32 + rg * 16 + kg * 4 + j;
            *(short*)((char*)Qs + row * 128 + (((c16b ^ (row & 7)) & 7) << 4) + (fr & 7) * 2) =
                (short)f2b(p);
          }
        }
#pragma unroll
        for (int j = 0; j < 4; ++j) l_run[rg][j] = l_run[rg][j] * a_[j] + psum[j];
#pragma unroll
        for (int dt = 0; dt < 4; ++dt)
#pragma unroll
          for (int j = 0; j < 4; ++j) acco[rg][dt][j] *= a_[j];
      }
      // ---- PV: 16 MFMA (P rows are wave-private; intra-wave LDS RAW is ordered) ----
#pragma unroll
      for (int rg = 0; rg < 2; ++rg) {
        const int prow = wid * 32 + rg * 16 + fr;
        const char* pp = (const char*)Qs + prow * 128;
#pragma unroll
        for (int kk = 0; kk < 2; ++kk) {
          const s16x8 pf = *reinterpret_cast<const s16x8*>(
              pp + ((((kk * 4 + kg) ^ (prow & 7)) & 7) << 4));
#pragma unroll
          for (int dt = 0; dt < 4; ++dt) {
            const int vrow = dt * 16 + fr;
            const s16x8 vf = *reinterpret_cast<const s16x8*>(
                (const char*)Vt + vrow * 128 + ((((kk * 4 + kg) ^ (vrow & 7)) & 7) << 4));
            acco[rg][dt] = __builtin_amdgcn_mfma_f32_16x16x32_bf16(pf, vf, acco[rg][dt], 0, 0, 0);
          }
        }
      }
    }
  }

  // ---- epilogue ----
#pragma unroll
  for (int off = 1; off < 16; off <<= 1)
#pragma unroll
    for (int rg = 0; rg < 2; ++rg)
#pragma unroll
      for (int j = 0; j < 4; ++j) l_run[rg][j] += __shfl_xor(l_run[rg][j], off);
  unsigned short* yp = (unsigned short*)yg + (size_t)bb * T_ * D_ + (size_t)hh * DH_;
#pragma unroll
  for (int rg = 0; rg < 2; ++rg) {
    float inv[4];
#pragma unroll
    for (int j = 0; j < 4; ++j) inv[j] = 1.0f / l_run[rg][j];
#pragma unroll
    for (int dt = 0; dt < 4; ++dt)
#pragma unroll
      for (int j = 0; j < 4; ++j) {
        const int row = qb * 128 + wid * 32 + rg * 16 + kg * 4 + j;
        yp[(size_t)row * D_ + dt * 16 + fr] = f2b(acco[rg][dt][j] * inv[j]);
      }
  }
}

extern "C" void kernel_launch(void* const* d_in, const int* in_sizes, int n_in,
                              void* d_out, int out_size, void* d_ws, size_t ws_size,
                              hipStream_t stream) {
  (void)in_sizes; (void)n_in; (void)out_size; (void)ws_size;
  const float* seq  = (const float*)d_in[0];
  const float* Wq   = (const float*)d_in[1];
  const float* bq   = (const float*)d_in[2];
  const float* Wk   = (const float*)d_in[3];
  const float* bk   = (const float*)d_in[4];
  const float* Wv   = (const float*)d_in[5];
  const float* bv   = (const float*)d_in[6];
  const float* Wp   = (const float*)d_in[7];
  const float* bp   = (const float*)d_in[8];
  const float* ln1g = (const float*)d_in[9];
  const float* ln1b = (const float*)d_in[10];
  const float* ln2g = (const float*)d_in[11];
  const float* ln2b = (const float*)d_in[12];
  const float* W1   = (const float*)d_in[13];
  const float* b1   = (const float*)d_in[14];
  const float* W2   = (const float*)d_in[15];
  const float* b2   = (const float*)d_in[16];
  const float* lnfg = (const float*)d_in[17];
  const float* lnfb = (const float*)d_in[18];

  float* x = (float*)d_out;
  char* ws = (char*)d_ws;
  const size_t MB = 1024ull * 1024ull;
  typedef __hip_bfloat16 bf16;
  bf16*  wtqkv = (bf16*)(ws + 0 * MB);    // [3072][1024]
  bf16*  wtp   = (bf16*)(ws + 6 * MB);    // [1024][1024]
  bf16*  wtF1  = (bf16*)(ws + 8 * MB);    // [4096][1024]
  bf16*  wtF2  = (bf16*)(ws + 16 * MB);   // [1024][4096]
  bf16*  hb    = (bf16*)(ws + 24 * MB);   // [4096][1024]
  bf16*  qkv   = (bf16*)(ws + 32 * MB);   // [4096][3072]
  bf16*  mid   = (bf16*)(ws + 56 * MB);   // [4096][4096]
  float* bqkv  = (float*)(ws + 88 * MB);  // [8][3072]

  hipMemcpyAsync(x, seq, (size_t)M_ * D_ * sizeof(float), hipMemcpyDeviceToDevice, stream);

  const dim3 blk(256);
  concat_bias<<<96, blk, 0, stream>>>(bq, bk, bv, bqkv);

  for (int i = 0; i < 8; ++i) {
    const size_t wo  = (size_t)i * D_ * D_;
    const size_t vo  = (size_t)i * D_;
    const size_t w1o = (size_t)i * D_ * 4 * D_;

    ln_kernel<true><<<M_, blk, 0, stream>>>(x, hb, ln1g + vo, ln1b + vo);
    TrAll ta;
    ta.wq = Wq + wo; ta.wk = Wk + wo; ta.wv = Wv + wo; ta.wp = Wp + wo;
    ta.w1 = W1 + w1o; ta.w2 = W2 + w1o;
    ta.dqkv = wtqkv; ta.dp = wtp; ta.d1 = wtF1; ta.d2 = wtF2;
    transpose_all<<<12288, blk, 0, stream>>>(ta);
    gemm_mfma<0, 128><<<dim3(24, 32), blk, 0, stream>>>(
        hb, wtqkv, bqkv + (size_t)i * QSTR_, qkv, QSTR_, 1024);
    attn_mfma<<<dim3(8, 16, 4), blk, 0, stream>>>(qkv, hb);
    gemm_mfma<1, 64><<<dim3(16, 32), blk, 0, stream>>>(hb, wtp, bp + vo, x, 1024, 1024);
    ln_kernel<true><<<M_, blk, 0, stream>>>(x, hb, ln2g + vo, ln2b + vo);
    gemm_mfma<2, 128><<<dim3(32, 32), blk, 0, stream>>>(
        hb, wtF1, b1 + (size_t)i * 4096, mid, 4096, 1024);
    gemm_mfma<1, 64><<<dim3(16, 32), blk, 0, stream>>>(
        mid, wtF2, b2 + vo, x, 1024, 4096);
  }
  ln_kernel<false><<<M_, blk, 0, stream>>>(x, x, lnfg, lnfb);
}